// Round 1
// baseline (397.310 us; speedup 1.0000x reference)
//
#include <hip/hip_runtime.h>
#include <hip/hip_bf16.h>

// MultiHeadAttention: B=2, S=2048, D=1024, H=16, DK=64
// Pipeline: cast->bf16, QKV proj GEMMs (MFMA), flash attention (MFMA), out proj.
// Workspace layout (needs >= 64 MiB):
//   qb/kb/vb  : [4096,1024] bf16 @ 0 / 8 MiB / 16 MiB
//   Wq/Wk/Wv/Wo bf16 [1024,1024] @ 24,26,28,30 MiB
//   qh/kh/vh  : [B,H,S,DK] bf16 @ 32 / 40 / 48 MiB
//   oc        : [4096,1024] bf16 @ 56 MiB   (attention output, concat layout)

using bf16x8 = __attribute__((ext_vector_type(8))) short;
using f32x4  = __attribute__((ext_vector_type(4))) float;

#define LDK 72  // 64 + 8 bf16 pad -> row stride 144 B (16B-aligned, breaks bank aliasing)

constexpr int Bc = 2, Sc = 2048, Dc = 1024, Hc = 16, DKc = 64;
constexpr int Mc = Bc * Sc;  // 4096

struct __align__(16) bfv8 { __hip_bfloat16 v[8]; };

// ---------------- cast fp32 -> bf16 ----------------
__global__ void cast_bf16_kernel(const float* __restrict__ src,
                                 __hip_bfloat16* __restrict__ dst, int n) {
  int i = (blockIdx.x * blockDim.x + threadIdx.x) * 4;
  if (i >= n) return;
  float4 x = *(const float4*)&src[i];
  dst[i + 0] = __float2bfloat16(x.x);
  dst[i + 1] = __float2bfloat16(x.y);
  dst[i + 2] = __float2bfloat16(x.z);
  dst[i + 3] = __float2bfloat16(x.w);
}

// ---------------- GEMM: Y = X @ W^T + bias ----------------
// X [M,K] bf16 row-major, W [N,K] bf16 row-major (both K-contiguous).
// mode 0: store bf16 permuted [B,H,S,DK]; mode 1: store fp32 [M,N].
__global__ __launch_bounds__(256) void gemm_bt(
    const __hip_bfloat16* __restrict__ X, const __hip_bfloat16* __restrict__ W,
    const float* __restrict__ bias, void* __restrict__ Y,
    int M, int N, int K, int mode) {
  __shared__ __align__(16) __hip_bfloat16 As[128 * LDK];
  __shared__ __align__(16) __hip_bfloat16 Bs[128 * LDK];
  const int tid = threadIdx.x;
  const int m0 = blockIdx.x * 128, n0 = blockIdx.y * 128;
  const int w = tid >> 6, lane = tid & 63, ln = lane & 15, quad = lane >> 4;
  const int wm = (w >> 1) * 64, wn = (w & 1) * 64;
  f32x4 acc[4][4] = {};
  for (int kb = 0; kb < K; kb += 64) {
#pragma unroll
    for (int p = 0; p < 4; ++p) {
      int idx = p * 256 + tid;
      int row = idx >> 3, c8 = (idx & 7) * 8;
      *(bf16x8*)&As[row * LDK + c8] =
          *(const bf16x8*)&X[(size_t)(m0 + row) * K + kb + c8];
      *(bf16x8*)&Bs[row * LDK + c8] =
          *(const bf16x8*)&W[(size_t)(n0 + row) * K + kb + c8];
    }
    __syncthreads();
#pragma unroll
    for (int ks = 0; ks < 64; ks += 32) {
      bf16x8 af[4], bf[4];
#pragma unroll
      for (int i = 0; i < 4; ++i)
        af[i] = *(bf16x8*)&As[(wm + i * 16 + ln) * LDK + ks + quad * 8];
#pragma unroll
      for (int j = 0; j < 4; ++j)
        bf[j] = *(bf16x8*)&Bs[(wn + j * 16 + ln) * LDK + ks + quad * 8];
#pragma unroll
      for (int i = 0; i < 4; ++i)
#pragma unroll
        for (int j = 0; j < 4; ++j)
          acc[i][j] = __builtin_amdgcn_mfma_f32_16x16x32_bf16(af[i], bf[j],
                                                              acc[i][j], 0, 0, 0);
    }
    __syncthreads();
  }
  // epilogue: C/D layout col=lane&15, row=quad*4+reg
#pragma unroll
  for (int i = 0; i < 4; ++i)
#pragma unroll
    for (int j = 0; j < 4; ++j)
#pragma unroll
      for (int r = 0; r < 4; ++r) {
        int mg = m0 + wm + i * 16 + quad * 4 + r;
        int ng = n0 + wn + j * 16 + ln;
        float val = acc[i][j][r] + bias[ng];
        if (mode == 0) {
          int b = mg >> 11, s = mg & 2047, h = ng >> 6, dk = ng & 63;
          ((__hip_bfloat16*)Y)[(((size_t)(b * Hc + h) * Sc + s) * DKc) + dk] =
              __float2bfloat16(val);
        } else {
          ((float*)Y)[(size_t)mg * N + ng] = val;
        }
      }
}

// ---------------- flash attention ----------------
// grid: (S/128, B*H). block 256 = 4 waves; wave w owns Q rows [w*32, w*32+32).
__global__ __launch_bounds__(256) void flash_attn(
    const __hip_bfloat16* __restrict__ qh, const __hip_bfloat16* __restrict__ kh,
    const __hip_bfloat16* __restrict__ vh, const int* __restrict__ mask,
    __hip_bfloat16* __restrict__ oc) {
  __shared__ __align__(16) __hip_bfloat16 Qs[128 * LDK];
  __shared__ __align__(16) __hip_bfloat16 Ks[64 * LDK];
  __shared__ __align__(16) __hip_bfloat16 Vt[64 * LDK];  // [dk][t] transposed
  __shared__ __align__(16) __hip_bfloat16 Ps[128 * LDK];
  const int tid = threadIdx.x;
  const int bh = blockIdx.y, b = bh >> 4, h = bh & 15;
  const int q0 = blockIdx.x * 128;
  const int w = tid >> 6, lane = tid & 63, ln = lane & 15, quad = lane >> 4;
  const size_t base = (size_t)bh * Sc * DKc;

  // stage Q tile [128,64]
#pragma unroll
  for (int p = 0; p < 4; ++p) {
    int idx = p * 256 + tid;
    int row = idx >> 3, c8 = (idx & 7) * 8;
    *(bf16x8*)&Qs[row * LDK + c8] =
        *(const bf16x8*)&qh[base + (size_t)(q0 + row) * DKc + c8];
  }
  __syncthreads();
  // preload Q fragments (A operand: m=lane&15, k=quad*8+j)
  bf16x8 qf[2][2];
#pragma unroll
  for (int mt = 0; mt < 2; ++mt)
#pragma unroll
    for (int ks = 0; ks < 2; ++ks)
      qf[mt][ks] = *(bf16x8*)&Qs[(w * 32 + mt * 16 + ln) * LDK + ks * 32 + quad * 8];

  float mrun[2][4], lrun[2][4];
  f32x4 Oacc[2][4] = {};
#pragma unroll
  for (int mt = 0; mt < 2; ++mt)
#pragma unroll
    for (int r = 0; r < 4; ++r) { mrun[mt][r] = -INFINITY; lrun[mt][r] = 0.f; }

  for (int t0 = 0; t0 < Sc; t0 += 64) {
    __syncthreads();  // previous iteration's Ks/Vt reads complete
#pragma unroll
    for (int p = 0; p < 2; ++p) {
      int idx = p * 256 + tid;
      int row = idx >> 3, c8 = (idx & 7) * 8;
      *(bf16x8*)&Ks[row * LDK + c8] =
          *(const bf16x8*)&kh[base + (size_t)(t0 + row) * DKc + c8];
      bfv8 vv = *(const bfv8*)&vh[base + (size_t)(t0 + row) * DKc + c8];
#pragma unroll
      for (int j = 0; j < 8; ++j) Vt[(c8 + j) * LDK + row] = vv.v[j];
    }
    __syncthreads();
    // scores: S = Q K^T   (B operand: n=lane&15 -> K row t, k contiguous)
    f32x4 sacc[2][4];
#pragma unroll
    for (int mt = 0; mt < 2; ++mt)
#pragma unroll
      for (int tt = 0; tt < 4; ++tt) {
        f32x4 a = {0.f, 0.f, 0.f, 0.f};
#pragma unroll
        for (int ks = 0; ks < 2; ++ks) {
          bf16x8 kf = *(bf16x8*)&Ks[(tt * 16 + ln) * LDK + ks * 32 + quad * 8];
          a = __builtin_amdgcn_mfma_f32_16x16x32_bf16(qf[mt][ks], kf, a, 0, 0, 0);
        }
        sacc[mt][tt] = a;
      }
    // online softmax: each quad owns rows quad*4+r of each 16-row tile
#pragma unroll
    for (int mt = 0; mt < 2; ++mt)
#pragma unroll
      for (int r = 0; r < 4; ++r) {
        int sg = q0 + w * 32 + mt * 16 + quad * 4 + r;
        float sv[4];
#pragma unroll
        for (int tt = 0; tt < 4; ++tt) {
          float s = sacc[mt][tt][r] * 0.125f;
          int tg = t0 + tt * 16 + ln;
          if (mask[(size_t)sg * Sc + tg] == 0) s = -1e9f;  // exact replace, as ref
          sv[tt] = s;
        }
        float mx = fmaxf(fmaxf(sv[0], sv[1]), fmaxf(sv[2], sv[3]));
#pragma unroll
        for (int d = 1; d < 16; d <<= 1) mx = fmaxf(mx, __shfl_xor(mx, d));
        float mnew = fmaxf(mrun[mt][r], mx);
        float alpha = exp2f((mrun[mt][r] - mnew) * 1.44269504f);
        mrun[mt][r] = mnew;
        float ls = 0.f;
#pragma unroll
        for (int tt = 0; tt < 4; ++tt) {
          float p = exp2f((sv[tt] - mnew) * 1.44269504f);
          ls += p;
          Ps[(w * 32 + mt * 16 + quad * 4 + r) * LDK + tt * 16 + ln] =
              __float2bfloat16(p);
        }
#pragma unroll
        for (int d = 1; d < 16; d <<= 1) ls += __shfl_xor(ls, d);
        lrun[mt][r] = lrun[mt][r] * alpha + ls;
#pragma unroll
        for (int nd = 0; nd < 4; ++nd) Oacc[mt][nd][r] *= alpha;
      }
    __syncthreads();  // Ps visible
    // O += P V  (A from Ps, B from Vt[dk][t])
#pragma unroll
    for (int ks = 0; ks < 2; ++ks) {
      bf16x8 pa[2], vb[4];
#pragma unroll
      for (int mt = 0; mt < 2; ++mt)
        pa[mt] = *(bf16x8*)&Ps[(w * 32 + mt * 16 + ln) * LDK + ks * 32 + quad * 8];
#pragma unroll
      for (int nd = 0; nd < 4; ++nd)
        vb[nd] = *(bf16x8*)&Vt[(nd * 16 + ln) * LDK + ks * 32 + quad * 8];
#pragma unroll
      for (int mt = 0; mt < 2; ++mt)
#pragma unroll
        for (int nd = 0; nd < 4; ++nd)
          Oacc[mt][nd] =
              __builtin_amdgcn_mfma_f32_16x16x32_bf16(pa[mt], vb[nd], Oacc[mt][nd], 0, 0, 0);
    }
  }
  // epilogue: O /= l, store to concat layout [B,S,D] bf16
#pragma unroll
  for (int mt = 0; mt < 2; ++mt)
#pragma unroll
    for (int nd = 0; nd < 4; ++nd)
#pragma unroll
      for (int r = 0; r < 4; ++r) {
        int sg = q0 + w * 32 + mt * 16 + quad * 4 + r;
        int dg = h * 64 + nd * 16 + ln;
        float o = Oacc[mt][nd][r] / lrun[mt][r];
        oc[(size_t)(b * Sc + sg) * Dc + dg] = __float2bfloat16(o);
      }
}

extern "C" void kernel_launch(void* const* d_in, const int* in_sizes, int n_in,
                              void* d_out, int out_size, void* d_ws, size_t ws_size,
                              hipStream_t stream) {
  const float* q  = (const float*)d_in[0];
  const float* k  = (const float*)d_in[1];
  const float* v  = (const float*)d_in[2];
  const int* mask = (const int*)d_in[3];
  const float* Wq = (const float*)d_in[4];
  const float* bq = (const float*)d_in[5];
  const float* Wk = (const float*)d_in[6];
  const float* bk = (const float*)d_in[7];
  const float* Wv = (const float*)d_in[8];
  const float* bv = (const float*)d_in[9];
  const float* Wo = (const float*)d_in[10];
  const float* bo = (const float*)d_in[11];

  char* ws = (char*)d_ws;
  const size_t MB = 1024 * 1024;
  __hip_bfloat16* qb  = (__hip_bfloat16*)(ws + 0 * MB);
  __hip_bfloat16* kb  = (__hip_bfloat16*)(ws + 8 * MB);
  __hip_bfloat16* vb  = (__hip_bfloat16*)(ws + 16 * MB);
  __hip_bfloat16* Wqb = (__hip_bfloat16*)(ws + 24 * MB);
  __hip_bfloat16* Wkb = (__hip_bfloat16*)(ws + 26 * MB);
  __hip_bfloat16* Wvb = (__hip_bfloat16*)(ws + 28 * MB);
  __hip_bfloat16* Wob = (__hip_bfloat16*)(ws + 30 * MB);
  __hip_bfloat16* qhd = (__hip_bfloat16*)(ws + 32 * MB);
  __hip_bfloat16* khd = (__hip_bfloat16*)(ws + 40 * MB);
  __hip_bfloat16* vhd = (__hip_bfloat16*)(ws + 48 * MB);
  __hip_bfloat16* oc  = (__hip_bfloat16*)(ws + 56 * MB);

  const int nQKV = Mc * Dc;   // 4194304
  const int nW = Dc * Dc;     // 1048576
  cast_bf16_kernel<<<nQKV / 1024, 256, 0, stream>>>(q, qb, nQKV);
  cast_bf16_kernel<<<nQKV / 1024, 256, 0, stream>>>(k, kb, nQKV);
  cast_bf16_kernel<<<nQKV / 1024, 256, 0, stream>>>(v, vb, nQKV);
  cast_bf16_kernel<<<nW / 1024, 256, 0, stream>>>(Wq, Wqb, nW);
  cast_bf16_kernel<<<nW / 1024, 256, 0, stream>>>(Wk, Wkb, nW);
  cast_bf16_kernel<<<nW / 1024, 256, 0, stream>>>(Wv, Wvb, nW);
  cast_bf16_kernel<<<nW / 1024, 256, 0, stream>>>(Wo, Wob, nW);

  dim3 gg(Mc / 128, Dc / 128);
  gemm_bt<<<gg, 256, 0, stream>>>(qb, Wqb, bq, qhd, Mc, Dc, Dc, 0);
  gemm_bt<<<gg, 256, 0, stream>>>(kb, Wkb, bk, khd, Mc, Dc, Dc, 0);
  gemm_bt<<<gg, 256, 0, stream>>>(vb, Wvb, bv, vhd, Mc, Dc, Dc, 0);

  flash_attn<<<dim3(Sc / 128, Bc * Hc), 256, 0, stream>>>(qhd, khd, vhd, mask, oc);

  gemm_bt<<<gg, 256, 0, stream>>>(oc, Wob, bo, d_out, Mc, Dc, Dc, 1);
}

// Round 2
// 394.056 us; speedup vs baseline: 1.0083x; 1.0083x over previous
//
#include <hip/hip_runtime.h>
#include <hip/hip_bf16.h>

// MultiHeadAttention: B=2, S=2048, D=1024, H=16, DK=64
// Pipeline: cast->bf16, Q/K proj GEMMs -> [B,H,S,DK], V proj GEMM -> [B,H,DK,S]
// (transposed), mask->bitmask, flash attention (MFMA, async LDS staging),
// out proj -> fp32.
// Workspace (64 MiB):
//   qb/kb/vb   : [4096,1024] bf16 @ 0 / 8 / 16 MiB
//   maskbits   : [2048,32] u64 @ 16 MiB (aliases vb; written after V GEMM)
//   Wq/Wk/Wv/Wo: bf16 @ 24/26/28/30 MiB
//   qhd/khd    : [B,H,S,DK] bf16 @ 32 / 40 MiB
//   vtd        : [B,H,DK,S] bf16 @ 48 MiB
//   oc         : [4096,1024] bf16 @ 56 MiB

using bf16x8 = __attribute__((ext_vector_type(8))) short;
using f32x4  = __attribute__((ext_vector_type(4))) float;

#define LDP 72  // padded stride for Ps (softmax P tile)

constexpr int Bc = 2, Sc = 2048, Dc = 1024, Hc = 16, DKc = 64;
constexpr int Mc = Bc * Sc;  // 4096

// async global->LDS, 16B per lane. LDS dest is wave-uniform base + lane*16.
__device__ inline void lds_load16(const void* g, void* l) {
  __builtin_amdgcn_global_load_lds(
      (const __attribute__((address_space(1))) unsigned int*)g,
      (__attribute__((address_space(3))) unsigned int*)l, 16, 0, 0);
}

// ---------------- cast fp32 -> bf16 ----------------
__global__ void cast_bf16_kernel(const float* __restrict__ src,
                                 __hip_bfloat16* __restrict__ dst, int n) {
  int i = (blockIdx.x * blockDim.x + threadIdx.x) * 4;
  if (i >= n) return;
  float4 x = *(const float4*)&src[i];
  dst[i + 0] = __float2bfloat16(x.x);
  dst[i + 1] = __float2bfloat16(x.y);
  dst[i + 2] = __float2bfloat16(x.z);
  dst[i + 3] = __float2bfloat16(x.w);
}

// ---------------- mask -> bit matrix ----------------
__global__ void mask_pack_kernel(const int* __restrict__ mask,
                                 unsigned long long* __restrict__ bits) {
  int i = blockIdx.x * blockDim.x + threadIdx.x;
  unsigned long long bal = __ballot(mask[i] != 0);
  if ((threadIdx.x & 63) == 0) bits[i >> 6] = bal;
}

// ---------------- GEMM: Y = (X @ W^T + bias) * scale ----------------
// X [M,K] bf16, W [N,K] bf16, K-contiguous. m97-style async swizzled staging.
// mode 0: bf16 [B,H,S,DK]; mode 1: fp32 [M,N]; mode 2: bf16 [B,H,DK,S] (V^T).
__global__ __launch_bounds__(256) void gemm_bt(
    const __hip_bfloat16* __restrict__ X, const __hip_bfloat16* __restrict__ W,
    const float* __restrict__ bias, void* __restrict__ Y,
    int M, int N, int K, int mode, float scale) {
  __shared__ __align__(16) __hip_bfloat16 As[128 * 64];  // swizzled, unpadded
  __shared__ __align__(16) __hip_bfloat16 Bs[128 * 64];
  const int tid = threadIdx.x;
  const int m0 = blockIdx.x * 128, n0 = blockIdx.y * 128;
  const int w = tid >> 6, lane = tid & 63, ln = lane & 15, quad = lane >> 4;
  const int wm = (w >> 1) * 64, wn = (w & 1) * 64;
  f32x4 acc[4][4] = {};
  for (int kb = 0; kb < K; kb += 64) {
    __syncthreads();  // protect LDS overwrite vs prev iter reads
#pragma unroll
    for (int i = 0; i < 4; ++i) {
      int flat = (w * 4 + i) * 1024 + lane * 16;  // bytes into 16KB tile
      int row = flat >> 7, cg = (flat >> 4) & 7;
      int gofs = row * K + kb + ((cg ^ (row & 7)) * 8);
      lds_load16(&X[(size_t)m0 * K + gofs], (char*)As + flat);
      lds_load16(&W[(size_t)n0 * K + gofs], (char*)Bs + flat);
    }
    __syncthreads();  // drains vmcnt -> tiles ready
#pragma unroll
    for (int ks = 0; ks < 2; ++ks) {
      bf16x8 af[4], bf[4];
#pragma unroll
      for (int i = 0; i < 4; ++i) {
        int row = wm + i * 16 + ln;
        af[i] = *(bf16x8*)((char*)As + row * 128 +
                           (((ks * 4 + quad) ^ (row & 7)) * 16));
      }
#pragma unroll
      for (int j = 0; j < 4; ++j) {
        int row = wn + j * 16 + ln;
        bf[j] = *(bf16x8*)((char*)Bs + row * 128 +
                           (((ks * 4 + quad) ^ (row & 7)) * 16));
      }
#pragma unroll
      for (int i = 0; i < 4; ++i)
#pragma unroll
        for (int j = 0; j < 4; ++j)
          acc[i][j] = __builtin_amdgcn_mfma_f32_16x16x32_bf16(af[i], bf[j],
                                                              acc[i][j], 0, 0, 0);
    }
  }
  // epilogue: C/D layout col=lane&15, row=quad*4+reg
#pragma unroll
  for (int i = 0; i < 4; ++i)
#pragma unroll
    for (int j = 0; j < 4; ++j)
#pragma unroll
      for (int r = 0; r < 4; ++r) {
        int mg = m0 + wm + i * 16 + quad * 4 + r;
        int ng = n0 + wn + j * 16 + ln;
        float val = (acc[i][j][r] + bias[ng]) * scale;
        if (mode == 0) {
          int b = mg >> 11, s = mg & 2047, h = ng >> 6, dk = ng & 63;
          ((__hip_bfloat16*)Y)[(((size_t)(b * Hc + h) * Sc + s) * DKc) + dk] =
              __float2bfloat16(val);
        } else if (mode == 1) {
          ((float*)Y)[(size_t)mg * N + ng] = val;
        } else {  // V^T: [B,H,DK,S]
          int b = mg >> 11, s = mg & 2047, h = ng >> 6, dk = ng & 63;
          ((__hip_bfloat16*)Y)[(((size_t)(b * Hc + h) * DKc + dk) * Sc) + s] =
              __float2bfloat16(val);
        }
      }
}

// ---------------- flash attention ----------------
// grid (S/128, B*H), 256 thr. Q pre-scaled by 1/8 in projection.
// qh [bh][s][dk], vt [bh][dk][s]. K/V tiles 64 wide, double-buffered async.
__global__ __launch_bounds__(256) void flash_attn(
    const __hip_bfloat16* __restrict__ qh, const __hip_bfloat16* __restrict__ kh,
    const __hip_bfloat16* __restrict__ vt,
    const unsigned long long* __restrict__ mbits,
    __hip_bfloat16* __restrict__ oc) {
  __shared__ __align__(16) __hip_bfloat16 QPs[128 * LDP];  // Q staging, then P
  __shared__ __align__(16) __hip_bfloat16 Ks[2][64 * 64];  // swizzled
  __shared__ __align__(16) __hip_bfloat16 Vs[2][64 * 64];  // swizzled, [dk][t]
  const int tid = threadIdx.x;
  const int bh = blockIdx.y, b = bh >> 4, h = bh & 15;
  const int q0 = blockIdx.x * 128;
  const int w = tid >> 6, lane = tid & 63, ln = lane & 15, quad = lane >> 4;
  const size_t base = (size_t)bh * Sc * DKc;  // same for qh/kh and vt

  // ---- stage Q tile [128,64] (contiguous 16KB), swizzled, async ----
#pragma unroll
  for (int i = 0; i < 4; ++i) {
    int flat = (w * 4 + i) * 1024 + lane * 16;
    int row = flat >> 7, cg = (flat >> 4) & 7;
    lds_load16(&qh[base + (size_t)(q0 + row) * 64 + ((cg ^ (row & 7)) * 8)],
               (char*)QPs + flat);
  }
  __syncthreads();
  bf16x8 qf[2][2];
#pragma unroll
  for (int mt = 0; mt < 2; ++mt)
#pragma unroll
    for (int ks = 0; ks < 2; ++ks) {
      int row = w * 32 + mt * 16 + ln;
      qf[mt][ks] = *(bf16x8*)((char*)QPs + row * 128 +
                              (((ks * 4 + quad) ^ (row & 7)) * 16));
    }
  // prefetch K/V tile 0 (QPs repurposed as Ps after next barrier)
#pragma unroll
  for (int i = 0; i < 2; ++i) {
    int flat = (w * 2 + i) * 1024 + lane * 16;
    int row = flat >> 7, cg = (flat >> 4) & 7;
    int sw8 = (cg ^ (row & 7)) * 8;
    lds_load16(&kh[base + row * 64 + sw8], (char*)&Ks[0][0] + flat);
    lds_load16(&vt[base + (size_t)row * Sc + sw8], (char*)&Vs[0][0] + flat);
  }

  float mrun[2][4], lrun[2][4];
  f32x4 Oacc[2][4] = {};
#pragma unroll
  for (int mt = 0; mt < 2; ++mt)
#pragma unroll
    for (int r = 0; r < 4; ++r) { mrun[mt][r] = -INFINITY; lrun[mt][r] = 0.f; }

  for (int it = 0; it < Sc / 64; ++it) {
    const int t0 = it * 64, bi = it & 1;
    __syncthreads();  // drains vmcnt: tile `it` ready; prev-iter LDS reads done
    if (it + 1 < Sc / 64) {
      const int nb = (it + 1) & 1, nt = t0 + 64;
#pragma unroll
      for (int i = 0; i < 2; ++i) {
        int flat = (w * 2 + i) * 1024 + lane * 16;
        int row = flat >> 7, cg = (flat >> 4) & 7;
        int sw8 = (cg ^ (row & 7)) * 8;
        lds_load16(&kh[base + (size_t)(nt + row) * 64 + sw8],
                   (char*)&Ks[nb][0] + flat);
        lds_load16(&vt[base + (size_t)row * Sc + nt + sw8],
                   (char*)&Vs[nb][0] + flat);
      }
    }
    // mask bit-words (one u64 covers this row x 64 t's), hoisted
    unsigned long long mw[2][4];
#pragma unroll
    for (int mt = 0; mt < 2; ++mt)
#pragma unroll
      for (int r = 0; r < 4; ++r) {
        int sg = q0 + w * 32 + mt * 16 + quad * 4 + r;
        mw[mt][r] = mbits[(size_t)sg * (Sc / 64) + it];
      }
    // scores S = Q K^T
    f32x4 sacc[2][4];
#pragma unroll
    for (int mt = 0; mt < 2; ++mt)
#pragma unroll
      for (int tt = 0; tt < 4; ++tt) {
        f32x4 a = {0.f, 0.f, 0.f, 0.f};
#pragma unroll
        for (int ks = 0; ks < 2; ++ks) {
          int row = tt * 16 + ln;
          bf16x8 kf = *(bf16x8*)((char*)&Ks[bi][0] + row * 128 +
                                 (((ks * 4 + quad) ^ (row & 7)) * 16));
          a = __builtin_amdgcn_mfma_f32_16x16x32_bf16(qf[mt][ks], kf, a, 0, 0, 0);
        }
        sacc[mt][tt] = a;
      }
    // online softmax; quad owns rows quad*4+r
#pragma unroll
    for (int mt = 0; mt < 2; ++mt)
#pragma unroll
      for (int r = 0; r < 4; ++r) {
        float sv[4];
#pragma unroll
        for (int tt = 0; tt < 4; ++tt) {
          float s = sacc[mt][tt][r];
          if (!((mw[mt][r] >> (tt * 16 + ln)) & 1ull)) s = -1e9f;
          sv[tt] = s;
        }
        float mx = fmaxf(fmaxf(sv[0], sv[1]), fmaxf(sv[2], sv[3]));
#pragma unroll
        for (int d = 1; d < 16; d <<= 1) mx = fmaxf(mx, __shfl_xor(mx, d));
        float mnew = fmaxf(mrun[mt][r], mx);
        float alpha = exp2f((mrun[mt][r] - mnew) * 1.44269504f);
        mrun[mt][r] = mnew;
        float ls = 0.f;
        int prow = w * 32 + mt * 16 + quad * 4 + r;
#pragma unroll
        for (int tt = 0; tt < 4; ++tt) {
          float p = exp2f((sv[tt] - mnew) * 1.44269504f);
          ls += p;
          QPs[prow * LDP + tt * 16 + ln] = __float2bfloat16(p);
        }
#pragma unroll
        for (int d = 1; d < 16; d <<= 1) ls += __shfl_xor(ls, d);
        lrun[mt][r] = lrun[mt][r] * alpha + ls;
#pragma unroll
        for (int nd = 0; nd < 4; ++nd) Oacc[mt][nd][r] *= alpha;
      }
    // LDS-only barrier: do NOT drain vmcnt (keeps next-tile DMA in flight)
    asm volatile("s_waitcnt lgkmcnt(0)\n\ts_barrier" ::: "memory");
    // O += P V
#pragma unroll
    for (int ks = 0; ks < 2; ++ks) {
      bf16x8 pa[2], vb[4];
#pragma unroll
      for (int mt = 0; mt < 2; ++mt)
        pa[mt] = *(bf16x8*)&QPs[(w * 32 + mt * 16 + ln) * LDP + ks * 32 + quad * 8];
#pragma unroll
      for (int nd = 0; nd < 4; ++nd) {
        int row = nd * 16 + ln;
        vb[nd] = *(bf16x8*)((char*)&Vs[bi][0] + row * 128 +
                            (((ks * 4 + quad) ^ (row & 7)) * 16));
      }
#pragma unroll
      for (int mt = 0; mt < 2; ++mt)
#pragma unroll
        for (int nd = 0; nd < 4; ++nd)
          Oacc[mt][nd] = __builtin_amdgcn_mfma_f32_16x16x32_bf16(
              pa[mt], vb[nd], Oacc[mt][nd], 0, 0, 0);
    }
  }
  // epilogue: O /= l -> concat layout [B,S,D] bf16
#pragma unroll
  for (int mt = 0; mt < 2; ++mt)
#pragma unroll
    for (int nd = 0; nd < 4; ++nd)
#pragma unroll
      for (int r = 0; r < 4; ++r) {
        int sg = q0 + w * 32 + mt * 16 + quad * 4 + r;
        int dg = h * 64 + nd * 16 + ln;
        float o = Oacc[mt][nd][r] / lrun[mt][r];
        oc[(size_t)(b * Sc + sg) * Dc + dg] = __float2bfloat16(o);
      }
}

extern "C" void kernel_launch(void* const* d_in, const int* in_sizes, int n_in,
                              void* d_out, int out_size, void* d_ws, size_t ws_size,
                              hipStream_t stream) {
  const float* q  = (const float*)d_in[0];
  const float* k  = (const float*)d_in[1];
  const float* v  = (const float*)d_in[2];
  const int* mask = (const int*)d_in[3];
  const float* Wq = (const float*)d_in[4];
  const float* bq = (const float*)d_in[5];
  const float* Wk = (const float*)d_in[6];
  const float* bk = (const float*)d_in[7];
  const float* Wv = (const float*)d_in[8];
  const float* bv = (const float*)d_in[9];
  const float* Wo = (const float*)d_in[10];
  const float* bo = (const float*)d_in[11];

  char* ws = (char*)d_ws;
  const size_t MB = 1024 * 1024;
  __hip_bfloat16* qb  = (__hip_bfloat16*)(ws + 0 * MB);
  __hip_bfloat16* kb  = (__hip_bfloat16*)(ws + 8 * MB);
  __hip_bfloat16* vb  = (__hip_bfloat16*)(ws + 16 * MB);
  unsigned long long* mbits = (unsigned long long*)(ws + 16 * MB);  // after V GEMM
  __hip_bfloat16* Wqb = (__hip_bfloat16*)(ws + 24 * MB);
  __hip_bfloat16* Wkb = (__hip_bfloat16*)(ws + 26 * MB);
  __hip_bfloat16* Wvb = (__hip_bfloat16*)(ws + 28 * MB);
  __hip_bfloat16* Wob = (__hip_bfloat16*)(ws + 30 * MB);
  __hip_bfloat16* qhd = (__hip_bfloat16*)(ws + 32 * MB);
  __hip_bfloat16* khd = (__hip_bfloat16*)(ws + 40 * MB);
  __hip_bfloat16* vtd = (__hip_bfloat16*)(ws + 48 * MB);
  __hip_bfloat16* oc  = (__hip_bfloat16*)(ws + 56 * MB);

  const int nQKV = Mc * Dc;
  const int nW = Dc * Dc;
  cast_bf16_kernel<<<nQKV / 1024, 256, 0, stream>>>(q, qb, nQKV);
  cast_bf16_kernel<<<nQKV / 1024, 256, 0, stream>>>(k, kb, nQKV);
  cast_bf16_kernel<<<nQKV / 1024, 256, 0, stream>>>(v, vb, nQKV);
  cast_bf16_kernel<<<nW / 1024, 256, 0, stream>>>(Wq, Wqb, nW);
  cast_bf16_kernel<<<nW / 1024, 256, 0, stream>>>(Wk, Wkb, nW);
  cast_bf16_kernel<<<nW / 1024, 256, 0, stream>>>(Wv, Wvb, nW);
  cast_bf16_kernel<<<nW / 1024, 256, 0, stream>>>(Wo, Wob, nW);

  dim3 gg(Mc / 128, Dc / 128);
  gemm_bt<<<gg, 256, 0, stream>>>(qb, Wqb, bq, qhd, Mc, Dc, Dc, 0, 0.125f);
  gemm_bt<<<gg, 256, 0, stream>>>(kb, Wkb, bk, khd, Mc, Dc, Dc, 0, 1.0f);
  gemm_bt<<<gg, 256, 0, stream>>>(vb, Wvb, bv, vtd, Mc, Dc, Dc, 2, 1.0f);
  // vb is dead now; pack mask into its region
  mask_pack_kernel<<<(Sc * Sc) / 256, 256, 0, stream>>>(mask, mbits);

  flash_attn<<<dim3(Sc / 128, Bc * Hc), 256, 0, stream>>>(qhd, khd, vtd, mbits, oc);

  gemm_bt<<<gg, 256, 0, stream>>>(oc, Wob, bo, d_out, Mc, Dc, Dc, 1, 0.0f + 1.0f);
}

// Round 3
// 296.853 us; speedup vs baseline: 1.3384x; 1.3274x over previous
//
#include <hip/hip_runtime.h>
#include <hip/hip_bf16.h>

// MultiHeadAttention: B=2, S=2048, D=1024, H=16, DK=64
// Round 3: no-max softmax (scores provably bounded), S^T orientation
// (lane-local softmax sums, wave-private P scratch, 1 barrier/iter),
// Q frags from global registers, dbuf 128x64 GEMMs at 2 blocks/CU.
// Workspace (64 MiB):
//   qb @0 (dead after Q GEMM -> mbits u64[2048][32] @0)
//   kb @8, vb @16, W @24/26/28/30, qhd @32, khd @40, vtd @48, oc @56

using bf16x8 = __attribute__((ext_vector_type(8))) short;
using f32x4  = __attribute__((ext_vector_type(4))) float;

constexpr int Bc = 2, Sc = 2048, Dc = 1024, Hc = 16, DKc = 64;
constexpr int Mc = Bc * Sc;  // 4096
#define LOG2E_OVER_SQRTDK 0.18033688011112042f  // log2(e)/8, folded into Q proj

__device__ __forceinline__ void lds_load16(const void* g, void* l) {
  __builtin_amdgcn_global_load_lds(
      (const __attribute__((address_space(1))) unsigned int*)g,
      (__attribute__((address_space(3))) unsigned int*)l, 16, 0, 0);
}

__device__ __forceinline__ unsigned pack2bf(float a, float b) {
  union { __hip_bfloat16 h; unsigned short s; } ua, ub;
  ua.h = __float2bfloat16(a);
  ub.h = __float2bfloat16(b);
  return (unsigned)ua.s | ((unsigned)ub.s << 16);
}

// ---------------- fused casts ----------------
__global__ void cast3_kernel(const float* __restrict__ a, const float* __restrict__ b,
                             const float* __restrict__ c, __hip_bfloat16* __restrict__ oa,
                             __hip_bfloat16* __restrict__ ob, __hip_bfloat16* __restrict__ oc2,
                             int n) {  // n per array; grid covers 3*n/4 threads
  int gid = blockIdx.x * blockDim.x + threadIdx.x;
  int per = n >> 2;
  int which = gid / per, i = (gid - which * per) * 4;
  const float* s = which == 0 ? a : (which == 1 ? b : c);
  __hip_bfloat16* d = which == 0 ? oa : (which == 1 ? ob : oc2);
  float4 x = *(const float4*)&s[i];
  d[i + 0] = __float2bfloat16(x.x);
  d[i + 1] = __float2bfloat16(x.y);
  d[i + 2] = __float2bfloat16(x.z);
  d[i + 3] = __float2bfloat16(x.w);
}

__global__ void cast4_kernel(const float* __restrict__ a, const float* __restrict__ b,
                             const float* __restrict__ c, const float* __restrict__ dd,
                             __hip_bfloat16* __restrict__ oa, __hip_bfloat16* __restrict__ ob,
                             __hip_bfloat16* __restrict__ oc2, __hip_bfloat16* __restrict__ od,
                             int n) {
  int gid = blockIdx.x * blockDim.x + threadIdx.x;
  int per = n >> 2;
  int which = gid / per, i = (gid - which * per) * 4;
  const float* s = which == 0 ? a : (which == 1 ? b : (which == 2 ? c : dd));
  __hip_bfloat16* d = which == 0 ? oa : (which == 1 ? ob : (which == 2 ? oc2 : od));
  float4 x = *(const float4*)&s[i];
  d[i + 0] = __float2bfloat16(x.x);
  d[i + 1] = __float2bfloat16(x.y);
  d[i + 2] = __float2bfloat16(x.z);
  d[i + 3] = __float2bfloat16(x.w);
}

// ---------------- mask -> bit matrix ----------------
__global__ void mask_pack_kernel(const int* __restrict__ mask,
                                 unsigned long long* __restrict__ bits) {
  int i = blockIdx.x * blockDim.x + threadIdx.x;
  unsigned long long bal = __ballot(mask[i] != 0);
  if ((threadIdx.x & 63) == 0) bits[i >> 6] = bal;
}

// ---------------- GEMM: Y = (X @ W^T + bias) * scale ----------------
// 128x64 tile, 512 blocks (2/CU), double-buffered K-loop (DMA overlaps MFMA).
// mode 0: bf16 [B,H,S,DK]; mode 1: fp32 [M,N]; mode 2: bf16 [B,H,DK,S].
__global__ __launch_bounds__(256) void gemm_bt(
    const __hip_bfloat16* __restrict__ X, const __hip_bfloat16* __restrict__ W,
    const float* __restrict__ bias, void* __restrict__ Y,
    int M, int N, int K, int mode, float scale) {
  __shared__ __align__(16) __hip_bfloat16 As[2][128 * 64];
  __shared__ __align__(16) __hip_bfloat16 Bs[2][64 * 64];
  const int tid = threadIdx.x;
  const int m0 = blockIdx.x * 128, n0 = blockIdx.y * 64;
  const int w = tid >> 6, lane = tid & 63, ln = lane & 15, quad = lane >> 4;
  const int wm = (w >> 1) * 64, wn = (w & 1) * 32;
  f32x4 acc[4][2] = {};

#define GEMM_STAGE(KB, BI)                                                    \
  {                                                                           \
    _Pragma("unroll") for (int i = 0; i < 4; ++i) {                           \
      int flat = (w * 4 + i) * 1024 + lane * 16;                              \
      int row = flat >> 7, cg = (flat >> 4) & 7;                              \
      lds_load16(&X[(size_t)(m0 + row) * K + (KB) + ((cg ^ (row & 7)) * 8)],  \
                 (char*)As[BI] + flat);                                       \
    }                                                                         \
    _Pragma("unroll") for (int i = 0; i < 2; ++i) {                           \
      int flat = (w * 2 + i) * 1024 + lane * 16;                              \
      int row = flat >> 7, cg = (flat >> 4) & 7;                              \
      lds_load16(&W[(size_t)(n0 + row) * K + (KB) + ((cg ^ (row & 7)) * 8)],  \
                 (char*)Bs[BI] + flat);                                       \
    }                                                                         \
  }

  GEMM_STAGE(0, 0);
  const int nkb = K / 64;
  for (int kb = 0; kb < nkb; ++kb) {
    const int bi = kb & 1;
    __syncthreads();  // tile kb ready (drains DMA); prev reads done
    if (kb + 1 < nkb) GEMM_STAGE((kb + 1) * 64, bi ^ 1);
    bf16x8 af[4][2], bf[2][2];
#pragma unroll
    for (int i = 0; i < 4; ++i) {
      int row = wm + i * 16 + ln;
#pragma unroll
      for (int kc = 0; kc < 2; ++kc)
        af[i][kc] = *(bf16x8*)((char*)As[bi] + row * 128 +
                               (((kc * 4 + quad) ^ (row & 7)) * 16));
    }
#pragma unroll
    for (int j = 0; j < 2; ++j) {
      int row = wn + j * 16 + ln;
#pragma unroll
      for (int kc = 0; kc < 2; ++kc)
        bf[j][kc] = *(bf16x8*)((char*)Bs[bi] + row * 128 +
                               (((kc * 4 + quad) ^ (row & 7)) * 16));
    }
#pragma unroll
    for (int i = 0; i < 4; ++i)
#pragma unroll
      for (int j = 0; j < 2; ++j)
#pragma unroll
        for (int kc = 0; kc < 2; ++kc)
          acc[i][j] = __builtin_amdgcn_mfma_f32_16x16x32_bf16(
              af[i][kc], bf[j][kc], acc[i][j], 0, 0, 0);
  }
  // epilogue: C/D layout col=lane&15, row=quad*4+reg
#pragma unroll
  for (int i = 0; i < 4; ++i)
#pragma unroll
    for (int j = 0; j < 2; ++j) {
      int ng = n0 + wn + j * 16 + ln;
      int mbase = m0 + wm + i * 16 + quad * 4;
      float vv[4];
#pragma unroll
      for (int r = 0; r < 4; ++r) vv[r] = (acc[i][j][r] + bias[ng]) * scale;
      if (mode == 0) {
#pragma unroll
        for (int r = 0; r < 4; ++r) {
          int mg = mbase + r, b = mg >> 11, s = mg & 2047, h = ng >> 6, dk = ng & 63;
          ((__hip_bfloat16*)Y)[(((size_t)(b * Hc + h) * Sc + s) * DKc) + dk] =
              __float2bfloat16(vv[r]);
        }
      } else if (mode == 1) {
#pragma unroll
        for (int r = 0; r < 4; ++r)
          ((float*)Y)[(size_t)(mbase + r) * N + ng] = vv[r];
      } else {  // mode 2: V^T [B,H,DK,S]; 4 consecutive s -> one 8B store
        int b = mbase >> 11, s = mbase & 2047, h = ng >> 6, dk = ng & 63;
        uint2 pk = {pack2bf(vv[0], vv[1]), pack2bf(vv[2], vv[3])};
        *(uint2*)&((__hip_bfloat16*)Y)[(((size_t)(b * Hc + h) * DKc + dk) * Sc) + s] = pk;
      }
    }
}

// ---------------- flash attention (S^T form, no-max softmax) ----------------
// grid (S/128, B*H), 256 thr = 4 waves; wave w owns q rows [w*32, w*32+32).
// qh pre-scaled by log2(e)/sqrt(DK). One barrier per t-tile (K/V dbuf).
__global__ __launch_bounds__(256) void flash_attn(
    const __hip_bfloat16* __restrict__ qh, const __hip_bfloat16* __restrict__ kh,
    const __hip_bfloat16* __restrict__ vt, const uint2* __restrict__ mbits,
    __hip_bfloat16* __restrict__ oc) {
  __shared__ __align__(16) __hip_bfloat16 Ks[2][64 * 64];  // [t][dk] swizzled
  __shared__ __align__(16) __hip_bfloat16 Vs[2][64 * 64];  // [dk][t] swizzled
  __shared__ __align__(16) __hip_bfloat16 Pt[4][32 * 72];  // per-wave [q][t] padded
  const int tid = threadIdx.x;
  const int bh = blockIdx.y, b = bh >> 4, h = bh & 15;
  const int q0 = blockIdx.x * 128;
  const int w = tid >> 6, lane = tid & 63, ln = lane & 15, quad = lane >> 4;
  const size_t base = (size_t)bh * Sc * DKc;
  const __hip_bfloat16* khb = kh + base;
  const __hip_bfloat16* vtb = vt + base;
  char* ptw = (char*)&Pt[w][0];

  // Q fragments straight from global (B operand: n=q=lane&15, k contiguous 16B)
  bf16x8 qf[2][2];
#pragma unroll
  for (int qt = 0; qt < 2; ++qt)
#pragma unroll
    for (int kc = 0; kc < 2; ++kc)
      qf[qt][kc] = *(const bf16x8*)&qh[base + (size_t)(q0 + w * 32 + qt * 16 + ln) * 64 +
                                       kc * 32 + quad * 8];

#define KV_STAGE(T0, BI)                                                      \
  {                                                                           \
    _Pragma("unroll") for (int i = 0; i < 2; ++i) {                           \
      int flat = (w * 2 + i) * 1024 + lane * 16;                              \
      int row = flat >> 7, cg = (flat >> 4) & 7;                              \
      int sw8 = (cg ^ (row & 7)) * 8;                                         \
      lds_load16(&khb[(size_t)((T0) + row) * 64 + sw8], (char*)Ks[BI] + flat);\
      lds_load16(&vtb[(size_t)row * Sc + (T0) + sw8], (char*)Vs[BI] + flat);  \
    }                                                                         \
  }

  KV_STAGE(0, 0);
  float lsum[2] = {0.f, 0.f};
  f32x4 Oacc[4][2] = {};

  for (int it = 0; it < Sc / 64; ++it) {
    const int bi = it & 1;
    __syncthreads();  // tile `it` DMA complete; prev-iter K/V reads done
    if (it + 1 < Sc / 64) KV_STAGE((it + 1) * 64, bi ^ 1);

    // S^T = K Q^T : rows t, cols q
    bf16x8 kf[4][2];
#pragma unroll
    for (int tt = 0; tt < 4; ++tt) {
      int row = tt * 16 + ln;
#pragma unroll
      for (int kc = 0; kc < 2; ++kc)
        kf[tt][kc] = *(bf16x8*)((char*)Ks[bi] + row * 128 +
                                (((kc * 4 + quad) ^ (row & 7)) * 16));
    }
    f32x4 sacc[2][4];
#pragma unroll
    for (int qt = 0; qt < 2; ++qt)
#pragma unroll
      for (int tt = 0; tt < 4; ++tt) {
        f32x4 a = {0.f, 0.f, 0.f, 0.f};
        a = __builtin_amdgcn_mfma_f32_16x16x32_bf16(kf[tt][0], qf[qt][0], a, 0, 0, 0);
        a = __builtin_amdgcn_mfma_f32_16x16x32_bf16(kf[tt][1], qf[qt][1], a, 0, 0, 0);
        sacc[qt][tt] = a;
      }
    // exp + mask + lane-local l accumulation + packed P^T writes (wave-private)
#pragma unroll
    for (int qt = 0; qt < 2; ++qt) {
      uint2 mw = mbits[(size_t)(q0 + w * 32 + qt * 16 + ln) * (Sc / 64) + it];
#pragma unroll
      for (int tt = 0; tt < 4; ++tt) {
        unsigned half = (tt & 2) ? mw.y : mw.x;
        unsigned pre = half >> ((tt & 1) * 16 + quad * 4);
        float p[4];
#pragma unroll
        for (int r = 0; r < 4; ++r) {
          float e = exp2f(sacc[qt][tt][r]);
          p[r] = (pre & (1u << r)) ? e : 0.f;
          lsum[qt] += p[r];
        }
        uint2 pk = {pack2bf(p[0], p[1]), pack2bf(p[2], p[3])};
        *(uint2*)(ptw + (qt * 16 + ln) * 144 + tt * 32 + quad * 8) = pk;
      }
    }
    // O^T += V^T P^T  (A = V^T rows d, B = P^T rows q; both t-contiguous)
    bf16x8 vf[4][2], pb[2][2];
#pragma unroll
    for (int dt = 0; dt < 4; ++dt) {
      int row = dt * 16 + ln;
#pragma unroll
      for (int kc = 0; kc < 2; ++kc)
        vf[dt][kc] = *(bf16x8*)((char*)Vs[bi] + row * 128 +
                                (((kc * 4 + quad) ^ (row & 7)) * 16));
    }
#pragma unroll
    for (int qt = 0; qt < 2; ++qt)
#pragma unroll
      for (int kc = 0; kc < 2; ++kc)
        pb[qt][kc] = *(bf16x8*)(ptw + (qt * 16 + ln) * 144 + kc * 64 + quad * 16);
#pragma unroll
    for (int dt = 0; dt < 4; ++dt)
#pragma unroll
      for (int qt = 0; qt < 2; ++qt) {
        Oacc[dt][qt] = __builtin_amdgcn_mfma_f32_16x16x32_bf16(
            vf[dt][0], pb[qt][0], Oacc[dt][qt], 0, 0, 0);
        Oacc[dt][qt] = __builtin_amdgcn_mfma_f32_16x16x32_bf16(
            vf[dt][1], pb[qt][1], Oacc[dt][qt], 0, 0, 0);
      }
  }

  // epilogue: l = quad-reduce(lsum); O^T/l -> transpose via wave scratch -> oc
  float linv[2];
#pragma unroll
  for (int qt = 0; qt < 2; ++qt) {
    float l = lsum[qt];
    l += __shfl_xor(l, 16);
    l += __shfl_xor(l, 32);
    linv[qt] = 1.f / fmaxf(l, 1e-30f);
  }
#pragma unroll
  for (int dt = 0; dt < 4; ++dt)
#pragma unroll
    for (int qt = 0; qt < 2; ++qt) {
      f32x4 o = Oacc[dt][qt];
      uint2 pk = {pack2bf(o[0] * linv[qt], o[1] * linv[qt]),
                  pack2bf(o[2] * linv[qt], o[3] * linv[qt])};
      *(uint2*)(ptw + (qt * 16 + ln) * 144 + dt * 32 + quad * 8) = pk;
    }
  __builtin_amdgcn_s_waitcnt(0);  // lgkm drain (wave-private scratch)
#pragma unroll
  for (int chunk = 0; chunk < 4; ++chunk) {
    int row = chunk * 8 + (lane >> 3);
    bf16x8 val = *(bf16x8*)(ptw + row * 144 + (lane & 7) * 16);
    int s = q0 + w * 32 + row;
    *(bf16x8*)&oc[(size_t)(b * Sc + s) * Dc + h * 64 + (lane & 7) * 8] = val;
  }
}

extern "C" void kernel_launch(void* const* d_in, const int* in_sizes, int n_in,
                              void* d_out, int out_size, void* d_ws, size_t ws_size,
                              hipStream_t stream) {
  const float* q  = (const float*)d_in[0];
  const float* k  = (const float*)d_in[1];
  const float* v  = (const float*)d_in[2];
  const int* mask = (const int*)d_in[3];
  const float* Wq = (const float*)d_in[4];
  const float* bq = (const float*)d_in[5];
  const float* Wk = (const float*)d_in[6];
  const float* bk = (const float*)d_in[7];
  const float* Wv = (const float*)d_in[8];
  const float* bv = (const float*)d_in[9];
  const float* Wo = (const float*)d_in[10];
  const float* bo = (const float*)d_in[11];

  char* ws = (char*)d_ws;
  const size_t MB = 1024 * 1024;
  __hip_bfloat16* qb  = (__hip_bfloat16*)(ws + 0 * MB);
  unsigned long long* mbits = (unsigned long long*)(ws + 0 * MB);  // after Q GEMM
  __hip_bfloat16* kb  = (__hip_bfloat16*)(ws + 8 * MB);
  __hip_bfloat16* vb  = (__hip_bfloat16*)(ws + 16 * MB);
  __hip_bfloat16* Wqb = (__hip_bfloat16*)(ws + 24 * MB);
  __hip_bfloat16* Wkb = (__hip_bfloat16*)(ws + 26 * MB);
  __hip_bfloat16* Wvb = (__hip_bfloat16*)(ws + 28 * MB);
  __hip_bfloat16* Wob = (__hip_bfloat16*)(ws + 30 * MB);
  __hip_bfloat16* qhd = (__hip_bfloat16*)(ws + 32 * MB);
  __hip_bfloat16* khd = (__hip_bfloat16*)(ws + 40 * MB);
  __hip_bfloat16* vtd = (__hip_bfloat16*)(ws + 48 * MB);
  __hip_bfloat16* oc  = (__hip_bfloat16*)(ws + 56 * MB);

  const int nQKV = Mc * Dc, nW = Dc * Dc;
  cast3_kernel<<<3 * (nQKV / 4) / 256, 256, 0, stream>>>(q, k, v, qb, kb, vb, nQKV);
  cast4_kernel<<<4 * (nW / 4) / 256, 256, 0, stream>>>(Wq, Wk, Wv, Wo, Wqb, Wkb,
                                                       Wvb, Wob, nW);

  dim3 gg(Mc / 128, Dc / 64);
  // Q projection: fold log2(e)/sqrt(DK) into output
  gemm_bt<<<gg, 256, 0, stream>>>(qb, Wqb, bq, qhd, Mc, Dc, Dc, 0, LOG2E_OVER_SQRTDK);
  // qb now dead -> pack mask into its region
  mask_pack_kernel<<<(Sc * Sc) / 256, 256, 0, stream>>>(mask, mbits);
  gemm_bt<<<gg, 256, 0, stream>>>(kb, Wkb, bk, khd, Mc, Dc, Dc, 0, 1.0f);
  gemm_bt<<<gg, 256, 0, stream>>>(vb, Wvb, bv, vtd, Mc, Dc, Dc, 2, 1.0f);

  flash_attn<<<dim3(Sc / 128, Bc * Hc), 256, 0, stream>>>(
      qhd, khd, vtd, (const uint2*)mbits, oc);

  gemm_bt<<<gg, 256, 0, stream>>>(oc, Wob, bo, d_out, Mc, Dc, Dc, 1, 1.0f);
}

// Round 5
// 251.326 us; speedup vs baseline: 1.5809x; 1.1811x over previous
//
#include <hip/hip_runtime.h>
#include <hip/hip_bf16.h>

// MultiHeadAttention: B=2, S=2048, D=1024, H=16, DK=64
// Round 5: round-4 structure with gemm_out W-staging fix (i*4096 -> i*8192;
// LDS dest steps 8 rows per i, source must too).
// Workspace (64 MiB): qb@0 kb@8 vb@16 | mbits@8 (after proj) | W@24..32 |
// qhd@32 khd@40 vtd@48 oc@56

using bf16x8 = __attribute__((ext_vector_type(8))) short;
using f32x4  = __attribute__((ext_vector_type(4))) float;

constexpr int Bc = 2, Sc = 2048, Dc = 1024, Hc = 16, DKc = 64;
constexpr int Mc = Bc * Sc;  // 4096
#define QSCALE 0.18033688011112042f  // log2(e)/sqrt(DK), folded into Q proj

__device__ __forceinline__ void lds_load16(const void* g, void* l) {
  __builtin_amdgcn_global_load_lds(
      (const __attribute__((address_space(1))) unsigned int*)g,
      (__attribute__((address_space(3))) unsigned int*)l, 16, 0, 0);
}

#if __has_builtin(__builtin_amdgcn_exp2f)
__device__ __forceinline__ float exp2_fast(float x) { return __builtin_amdgcn_exp2f(x); }
#else
__device__ __forceinline__ float exp2_fast(float x) {
  float r;
  asm("v_exp_f32 %0, %1\n\ts_nop 0" : "=v"(r) : "v"(x));
  return r;
}
#endif

// truncating bf16x2 pack: result = [hi16(b) : hi16(a)] — one v_perm_b32
__device__ __forceinline__ unsigned pack_trunc(float a, float b) {
  return __builtin_amdgcn_perm(__float_as_uint(b), __float_as_uint(a), 0x07060302u);
}

// RNE pack (epilogues only)
__device__ __forceinline__ unsigned pack2bf(float a, float b) {
  union { __hip_bfloat16 h; unsigned short s; } ua, ub;
  ua.h = __float2bfloat16(a);
  ub.h = __float2bfloat16(b);
  return (unsigned)ua.s | ((unsigned)ub.s << 16);
}

// ---------------- fused casts ----------------
__global__ void cast3_kernel(const float* __restrict__ a, const float* __restrict__ b,
                             const float* __restrict__ c, __hip_bfloat16* __restrict__ oa,
                             __hip_bfloat16* __restrict__ ob, __hip_bfloat16* __restrict__ oc2,
                             int n) {
  int gid = blockIdx.x * blockDim.x + threadIdx.x;
  int per = n >> 2;
  int which = gid / per, i = (gid - which * per) * 4;
  const float* s = which == 0 ? a : (which == 1 ? b : c);
  __hip_bfloat16* d = which == 0 ? oa : (which == 1 ? ob : oc2);
  float4 x = *(const float4*)&s[i];
  d[i + 0] = __float2bfloat16(x.x);
  d[i + 1] = __float2bfloat16(x.y);
  d[i + 2] = __float2bfloat16(x.z);
  d[i + 3] = __float2bfloat16(x.w);
}

__global__ void cast4_kernel(const float* __restrict__ a, const float* __restrict__ b,
                             const float* __restrict__ c, const float* __restrict__ dd,
                             __hip_bfloat16* __restrict__ oa, __hip_bfloat16* __restrict__ ob,
                             __hip_bfloat16* __restrict__ oc2, __hip_bfloat16* __restrict__ od,
                             int n) {
  int gid = blockIdx.x * blockDim.x + threadIdx.x;
  int per = n >> 2;
  int which = gid / per, i = (gid - which * per) * 4;
  const float* s = which == 0 ? a : (which == 1 ? b : (which == 2 ? c : dd));
  __hip_bfloat16* d = which == 0 ? oa : (which == 1 ? ob : (which == 2 ? oc2 : od));
  float4 x = *(const float4*)&s[i];
  d[i + 0] = __float2bfloat16(x.x);
  d[i + 1] = __float2bfloat16(x.y);
  d[i + 2] = __float2bfloat16(x.z);
  d[i + 3] = __float2bfloat16(x.w);
}

// ---------------- mask -> bit matrix ----------------
__global__ void mask_pack_kernel(const int* __restrict__ mask,
                                 unsigned long long* __restrict__ bits) {
  int i = blockIdx.x * blockDim.x + threadIdx.x;
  unsigned long long bal = __ballot(mask[i] != 0);
  if ((threadIdx.x & 63) == 0) bits[i >> 6] = bal;
}

// ---------------- fused QKV projection ----------------
// grid (32, 24): n0 = by*128 in [0,3072). which = n0>>10 selects {Q,K,V}.
// m97 structure: 128x128 tile, BK=64, single LDS buffer, 2 barriers/iter.
__global__ __launch_bounds__(256, 3) void proj_qkv(
    const __hip_bfloat16* __restrict__ qb, const __hip_bfloat16* __restrict__ kb,
    const __hip_bfloat16* __restrict__ vb, const __hip_bfloat16* __restrict__ Wcat,
    const float* __restrict__ bq, const float* __restrict__ bk,
    const float* __restrict__ bv, __hip_bfloat16* __restrict__ qhd,
    __hip_bfloat16* __restrict__ khd, __hip_bfloat16* __restrict__ vtd) {
  __shared__ __align__(16) __hip_bfloat16 As[128 * 64];
  __shared__ __align__(16) __hip_bfloat16 Bs[128 * 64];
  const int tid = threadIdx.x;
  const int m0 = blockIdx.x * 128, n0 = blockIdx.y * 128;
  const int which = n0 >> 10, nl0 = n0 & 1023;
  const __hip_bfloat16* X = which == 0 ? qb : (which == 1 ? kb : vb);
  const float* bias = which == 0 ? bq : (which == 1 ? bk : bv);
  const int w = tid >> 6, lane = tid & 63, ln = lane & 15, quad = lane >> 4;
  const int swz = ((lane & 7) ^ (lane >> 3)) * 8;  // element swizzle (row&7 == lane>>3)
  const int rk0 = ln * 128 + ((quad ^ (ln & 7)) * 16);
  const int rk1 = ln * 128 + (((quad + 4) ^ (ln & 7)) * 16);
  const int aoff = (m0 + w * 32 + (lane >> 3)) * 1024 + swz;
  const int boff = (n0 + w * 32 + (lane >> 3)) * 1024 + swz;
  char* aF = (char*)As + (w >> 1) * 8192;
  char* bF = (char*)Bs + (w & 1) * 8192;
  char* aDst = (char*)As + w * 4096 + lane * 16;
  char* bDst = (char*)Bs + w * 4096 + lane * 16;
  f32x4 acc[4][4] = {};
  int ko = 0;
  for (int kb64 = 0; kb64 < 16; ++kb64, ko += 64) {
#pragma unroll
    for (int i = 0; i < 4; ++i) {
      lds_load16(&X[aoff + i * 8192 + ko], aDst + i * 1024);
      lds_load16(&Wcat[boff + i * 8192 + ko], bDst + i * 1024);
    }
    __syncthreads();
    bf16x8 af[4][2], bf[4][2];
#pragma unroll
    for (int i = 0; i < 4; ++i) {
      af[i][0] = *(bf16x8*)(aF + i * 2048 + rk0);
      af[i][1] = *(bf16x8*)(aF + i * 2048 + rk1);
      bf[i][0] = *(bf16x8*)(bF + i * 2048 + rk0);
      bf[i][1] = *(bf16x8*)(bF + i * 2048 + rk1);
    }
#pragma unroll
    for (int i = 0; i < 4; ++i)
#pragma unroll
      for (int j = 0; j < 4; ++j) {
        acc[i][j] = __builtin_amdgcn_mfma_f32_16x16x32_bf16(af[i][0], bf[j][0],
                                                            acc[i][j], 0, 0, 0);
        acc[i][j] = __builtin_amdgcn_mfma_f32_16x16x32_bf16(af[i][1], bf[j][1],
                                                            acc[i][j], 0, 0, 0);
      }
    __syncthreads();
  }
  // epilogue: C/D col=lane&15, row=quad*4+reg
  const int wm = (w >> 1) * 64, wn = (w & 1) * 64;
#pragma unroll
  for (int i = 0; i < 4; ++i)
#pragma unroll
    for (int j = 0; j < 4; ++j) {
      int ngl = nl0 + wn + j * 16 + ln;  // local n in [0,1024)
      int mbase = m0 + wm + i * 16 + quad * 4;
      float bb = bias[ngl];
      float vv[4];
#pragma unroll
      for (int r = 0; r < 4; ++r) vv[r] = acc[i][j][r] + bb;
      int h = ngl >> 6, dk = ngl & 63;
      int b = mbase >> 11, s = mbase & 2047;
      if (which == 0) {
#pragma unroll
        for (int r = 0; r < 4; ++r)
          qhd[(((size_t)(b * Hc + h) * Sc + s + r) * DKc) + dk] =
              __float2bfloat16(vv[r] * QSCALE);
      } else if (which == 1) {
#pragma unroll
        for (int r = 0; r < 4; ++r)
          khd[(((size_t)(b * Hc + h) * Sc + s + r) * DKc) + dk] =
              __float2bfloat16(vv[r]);
      } else {  // V^T [B,H,DK,S]: 4 consecutive s -> one 8B store
        uint2 pk = {pack2bf(vv[0], vv[1]), pack2bf(vv[2], vv[3])};
        *(uint2*)&vtd[(((size_t)(b * Hc + h) * DKc + dk) * Sc) + s] = pk;
      }
    }
}

// ---------------- out projection: Y = oc @ Wo^T + bo (fp32) ----------------
// 128x64 tile, double-buffered.
__global__ __launch_bounds__(256, 2) void gemm_out(
    const __hip_bfloat16* __restrict__ X, const __hip_bfloat16* __restrict__ W,
    const float* __restrict__ bias, float* __restrict__ Y) {
  __shared__ __align__(16) __hip_bfloat16 As[2][128 * 64];
  __shared__ __align__(16) __hip_bfloat16 Bs[2][64 * 64];
  const int tid = threadIdx.x;
  const int m0 = blockIdx.x * 128, n0 = blockIdx.y * 64;
  const int w = tid >> 6, lane = tid & 63, ln = lane & 15, quad = lane >> 4;
  const int wm = (w >> 1) * 64, wn = (w & 1) * 32;
  const int swz = ((lane & 7) ^ (lane >> 3)) * 8;
  const int rk0 = ln * 128 + ((quad ^ (ln & 7)) * 16);
  const int rk1 = ln * 128 + (((quad + 4) ^ (ln & 7)) * 16);
  const int aoff = (m0 + w * 32 + (lane >> 3)) * 1024 + swz;
  const int boff = (n0 + w * 16 + (lane >> 3)) * 1024 + swz;
  f32x4 acc[4][2] = {};

  // LDS dest rows step 8 per i (i*1024 bytes) -> global source must step 8 rows
  // (i*8192 elements). i*4096 here was the round-4 correctness bug.
#define OSTAGE(KO, BI)                                                        \
  {                                                                           \
    _Pragma("unroll") for (int i = 0; i < 4; ++i)                             \
        lds_load16(&X[aoff + i * 8192 + (KO)],                                \
                   (char*)As[BI] + w * 4096 + lane * 16 + i * 1024);          \
    _Pragma("unroll") for (int i = 0; i < 2; ++i)                             \
        lds_load16(&W[boff + i * 8192 + (KO)],                                \
                   (char*)Bs[BI] + w * 2048 + lane * 16 + i * 1024);          \
  }

  OSTAGE(0, 0);
  for (int kb64 = 0; kb64 < 16; ++kb64) {
    const int bi = kb64 & 1;
    __syncthreads();
    if (kb64 + 1 < 16) OSTAGE((kb64 + 1) * 64, bi ^ 1);
    bf16x8 af[4][2], bf[2][2];
#pragma unroll
    for (int i = 0; i < 4; ++i) {
      af[i][0] = *(bf16x8*)((char*)As[bi] + wm * 128 + i * 2048 + rk0);
      af[i][1] = *(bf16x8*)((char*)As[bi] + wm * 128 + i * 2048 + rk1);
    }
#pragma unroll
    for (int j = 0; j < 2; ++j) {
      bf[j][0] = *(bf16x8*)((char*)Bs[bi] + wn * 128 + j * 2048 + rk0);
      bf[j][1] = *(bf16x8*)((char*)Bs[bi] + wn * 128 + j * 2048 + rk1);
    }
#pragma unroll
    for (int i = 0; i < 4; ++i)
#pragma unroll
      for (int j = 0; j < 2; ++j) {
        acc[i][j] = __builtin_amdgcn_mfma_f32_16x16x32_bf16(af[i][0], bf[j][0],
                                                            acc[i][j], 0, 0, 0);
        acc[i][j] = __builtin_amdgcn_mfma_f32_16x16x32_bf16(af[i][1], bf[j][1],
                                                            acc[i][j], 0, 0, 0);
      }
  }
#pragma unroll
  for (int i = 0; i < 4; ++i)
#pragma unroll
    for (int j = 0; j < 2; ++j) {
      int ng = n0 + wn + j * 16 + ln;
      int mbase = m0 + wm + i * 16 + quad * 4;
      float bb = bias[ng];
#pragma unroll
      for (int r = 0; r < 4; ++r)
        Y[(size_t)(mbase + r) * Dc + ng] = acc[i][j][r] + bb;
    }
}

// ---------------- flash attention (S^T, no-max, VALU-lean) ----------------
// grid (S/128, B*H), 256 thr. qh pre-scaled by log2(e)/8.
// LDS: Ks[2]@0 (16K), Vs[2]@16384 (16K), Pt@32768 (4 waves x 4608B).
__global__ __launch_bounds__(256, 2) void flash_attn(
    const __hip_bfloat16* __restrict__ qh, const __hip_bfloat16* __restrict__ kh,
    const __hip_bfloat16* __restrict__ vt, const uint4* __restrict__ mb4,
    __hip_bfloat16* __restrict__ oc) {
  __shared__ __align__(16) char L[51200];
  const int tid = threadIdx.x;
  const int bh = blockIdx.y, b = bh >> 4, h = bh & 15;
  const int q0 = blockIdx.x * 128;
  const int w = tid >> 6, lane = tid & 63, ln = lane & 15, quad = lane >> 4;
  const size_t base = (size_t)bh * Sc * DKc;
  const __hip_bfloat16* khb = kh + base;
  const __hip_bfloat16* vtb = vt + base;

  // Q fragments from global (B operand: n=q=lane&15, k=quad*8+j)
  bf16x8 qf[2][2];
#pragma unroll
  for (int qt = 0; qt < 2; ++qt)
#pragma unroll
    for (int kc = 0; kc < 2; ++kc)
      qf[qt][kc] = *(const bf16x8*)&qh[base +
          (size_t)(q0 + w * 32 + qt * 16 + ln) * 64 + kc * 32 + quad * 8];

  // hoisted addresses
  const int swz = ((lane & 7) ^ (lane >> 3)) * 8;
  const int rk0 = ln * 128 + ((quad ^ (ln & 7)) * 16);
  const int rk1 = ln * 128 + (((quad + 4) ^ (ln & 7)) * 16);
  const int rPw = 32768 + w * 4608 + ln * 144 + quad * 8;
  const int rPb = 32768 + w * 4608 + ln * 144 + quad * 16;
  char* dmaL = L + w * 2048 + lane * 16;
  int koff = (w * 16 + (lane >> 3)) * 64 + swz;        // += 4096/tile
  int voff0 = (w * 16 + (lane >> 3)) * Sc + swz;       // += 64/tile
  int voff1 = voff0 + 8 * Sc;
  int midx0 = (q0 + w * 32 + ln) * 16;                 // uint4 index, += 1 per 2 tiles
  int midx1 = midx0 + 256;
  const int sh0 = quad * 4, sh1 = quad * 4 + 16;

#define KV_DMA(BI)                                                            \
  {                                                                           \
    lds_load16(khb + koff, dmaL + (BI)*8192);                                 \
    lds_load16(khb + koff + 512, dmaL + (BI)*8192 + 1024);                    \
    lds_load16(vtb + voff0, dmaL + 16384 + (BI)*8192);                        \
    lds_load16(vtb + voff1, dmaL + 16384 + (BI)*8192 + 1024);                 \
  }

  float lsum[2] = {0.f, 0.f};
  f32x4 Oacc[4][2] = {};
  KV_DMA(0);  // tile 0

#define FTILE(BUF, LO0, HI0, LO1, HI1)                                        \
  {                                                                           \
    bf16x8 kf[4][2];                                                          \
    _Pragma("unroll") for (int tt = 0; tt < 4; ++tt) {                        \
      kf[tt][0] = *(bf16x8*)(L + (BUF)*8192 + tt * 2048 + rk0);               \
      kf[tt][1] = *(bf16x8*)(L + (BUF)*8192 + tt * 2048 + rk1);               \
    }                                                                         \
    _Pragma("unroll") for (int qt = 0; qt < 2; ++qt) {                        \
      f32x4 s[4];                                                             \
      _Pragma("unroll") for (int tt = 0; tt < 4; ++tt) {                      \
        f32x4 z = {0.f, 0.f, 0.f, 0.f};                                       \
        z = __builtin_amdgcn_mfma_f32_16x16x32_bf16(kf[tt][0], qf[qt][0], z,  \
                                                    0, 0, 0);                 \
        s[tt] = __builtin_amdgcn_mfma_f32_16x16x32_bf16(kf[tt][1], qf[qt][1], \
                                                        z, 0, 0, 0);          \
      }                                                                       \
      unsigned lo = qt ? (LO1) : (LO0), hi = qt ? (HI1) : (HI0);              \
      _Pragma("unroll") for (int tt = 0; tt < 4; ++tt) {                      \
        unsigned word = (tt & 2) ? hi : lo;                                   \
        unsigned pre = word >> ((tt & 1) ? sh1 : sh0);                        \
        float p[4];                                                           \
        _Pragma("unroll") for (int r = 0; r < 4; ++r) {                       \
          float e = exp2_fast(s[tt][r]);                                      \
          p[r] = (pre & (1u << r)) ? e : 0.f;                                 \
          lsum[qt] += p[r];                                                   \
        }                                                                     \
        uint2 pk = {pack_trunc(p[0], p[1]), pack_trunc(p[2], p[3])};          \
        *(uint2*)(L + rPw + qt * 2304 + tt * 32) = pk;                        \
      }                                                                       \
    }                                                                         \
    bf16x8 vf[4][2], pb[2][2];                                                \
    _Pragma("unroll") for (int dt = 0; dt < 4; ++dt) {                        \
      vf[dt][0] = *(bf16x8*)(L + 16384 + (BUF)*8192 + dt * 2048 + rk0);       \
      vf[dt][1] = *(bf16x8*)(L + 16384 + (BUF)*8192 + dt * 2048 + rk1);       \
    }                                                                         \
    _Pragma("unroll") for (int qt = 0; qt < 2; ++qt) {                        \
      pb[qt][0] = *(bf16x8*)(L + rPb + qt * 2304);                            \
      pb[qt][1] = *(bf16x8*)(L + rPb + qt * 2304 + 64);                       \
    }                                                                         \
    _Pragma("unroll") for (int dt = 0; dt < 4; ++dt)                          \
        _Pragma("unroll") for (int qt = 0; qt < 2; ++qt) {                    \
      Oacc[dt][qt] = __builtin_amdgcn_mfma_f32_16x16x32_bf16(                 \
          vf[dt][0], pb[qt][0], Oacc[dt][qt], 0, 0, 0);                       \
      Oacc[dt][qt] = __builtin_amdgcn_mfma_f32_16x16x32_bf16(                 \
          vf[dt][1], pb[qt][1], Oacc[dt][qt], 0, 0, 0);                       \
    }                                                                         \
  }

  for (int it2 = 0; it2 < 16; ++it2) {
    // ---- tile 2*it2 (buf 0) ----
    __syncthreads();  // drains this tile's DMA; prior LDS reads done
    uint4 mq0 = mb4[midx0], mq1 = mb4[midx1];  // masks for both tiles (issued
    ++midx0; ++midx1;                          // BEFORE next DMA: no forced drain)
    koff += 4096; voff0 += 64; voff1 += 64;
    KV_DMA(1);  // tile 2*it2+1 (always exists)
    FTILE(0, mq0.x, mq0.y, mq1.x, mq1.y);
    // ---- tile 2*it2+1 (buf 1) ----
    __syncthreads();
    if (it2 < 15) {
      koff += 4096; voff0 += 64; voff1 += 64;
      KV_DMA(0);
    }
    FTILE(1, mq0.z, mq0.w, mq1.z, mq1.w);
  }

  // epilogue: l = quad-reduce; O^T/l -> transpose via wave scratch -> oc
  float linv[2];
#pragma unroll
  for (int qt = 0; qt < 2; ++qt) {
    float l = lsum[qt];
    l += __shfl_xor(l, 16);
    l += __shfl_xor(l, 32);
    linv[qt] = 1.f / fmaxf(l, 1e-30f);
  }
#pragma unroll
  for (int dt = 0; dt < 4; ++dt)
#pragma unroll
    for (int qt = 0; qt < 2; ++qt) {
      f32x4 o = Oacc[dt][qt];
      uint2 pk = {pack2bf(o[0] * linv[qt], o[1] * linv[qt]),
                  pack2bf(o[2] * linv[qt], o[3] * linv[qt])};
      *(uint2*)(L + rPw + qt * 2304 + dt * 32) = pk;
    }
  __builtin_amdgcn_s_waitcnt(0);
#pragma unroll
  for (int chunk = 0; chunk < 4; ++chunk) {
    int row = chunk * 8 + (lane >> 3);
    bf16x8 val = *(bf16x8*)(L + 32768 + w * 4608 + row * 144 + (lane & 7) * 16);
    int s = q0 + w * 32 + row;
    *(bf16x8*)&oc[(size_t)(b * Sc + s) * Dc + h * 64 + (lane & 7) * 8] = val;
  }
}

extern "C" void kernel_launch(void* const* d_in, const int* in_sizes, int n_in,
                              void* d_out, int out_size, void* d_ws, size_t ws_size,
                              hipStream_t stream) {
  const float* q  = (const float*)d_in[0];
  const float* k  = (const float*)d_in[1];
  const float* v  = (const float*)d_in[2];
  const int* mask = (const int*)d_in[3];
  const float* Wq = (const float*)d_in[4];
  const float* bq = (const float*)d_in[5];
  const float* Wk = (const float*)d_in[6];
  const float* bk = (const float*)d_in[7];
  const float* Wv = (const float*)d_in[8];
  const float* bv = (const float*)d_in[9];
  const float* Wo = (const float*)d_in[10];
  const float* bo = (const float*)d_in[11];

  char* ws = (char*)d_ws;
  const size_t MB = 1024 * 1024;
  __hip_bfloat16* qb  = (__hip_bfloat16*)(ws + 0 * MB);
  __hip_bfloat16* kb  = (__hip_bfloat16*)(ws + 8 * MB);
  unsigned long long* mbits = (unsigned long long*)(ws + 8 * MB);  // after proj
  __hip_bfloat16* vb  = (__hip_bfloat16*)(ws + 16 * MB);
  __hip_bfloat16* Wqb = (__hip_bfloat16*)(ws + 24 * MB);  // Wq|Wk|Wv contiguous
  __hip_bfloat16* Wkb = (__hip_bfloat16*)(ws + 26 * MB);
  __hip_bfloat16* Wvb = (__hip_bfloat16*)(ws + 28 * MB);
  __hip_bfloat16* Wob = (__hip_bfloat16*)(ws + 30 * MB);
  __hip_bfloat16* qhd = (__hip_bfloat16*)(ws + 32 * MB);
  __hip_bfloat16* khd = (__hip_bfloat16*)(ws + 40 * MB);
  __hip_bfloat16* vtd = (__hip_bfloat16*)(ws + 48 * MB);
  __hip_bfloat16* oc  = (__hip_bfloat16*)(ws + 56 * MB);

  const int nQKV = Mc * Dc, nW = Dc * Dc;
  cast3_kernel<<<3 * (nQKV / 4) / 256, 256, 0, stream>>>(q, k, v, qb, kb, vb, nQKV);
  cast4_kernel<<<4 * (nW / 4) / 256, 256, 0, stream>>>(Wq, Wk, Wv, Wo, Wqb, Wkb,
                                                       Wvb, Wob, nW);

  proj_qkv<<<dim3(Mc / 128, 3 * Dc / 128), 256, 0, stream>>>(
      qb, kb, vb, Wqb, bq, bk, bv, qhd, khd, vtd);

  // kb dead now -> pack mask into its region
  mask_pack_kernel<<<(Sc * Sc) / 256, 256, 0, stream>>>(mask, mbits);

  flash_attn<<<dim3(Sc / 128, Bc * Hc), 256, 0, stream>>>(
      qhd, khd, vtd, (const uint4*)mbits, oc);

  gemm_out<<<dim3(Mc / 128, Dc / 64), 256, 0, stream>>>(oc, Wob, bo, (float*)d_out);
}

// Round 6
// 245.370 us; speedup vs baseline: 1.6192x; 1.0243x over previous
//
#include <hip/hip_runtime.h>
#include <hip/hip_bf16.h>

// MultiHeadAttention: B=2, S=2048, D=1024, H=16, DK=64
// Round 6: XCD-aware block swizzle (proj/out/flash), flash t-split x2 with
// fp32 partials + reduce kernel, l via ones-MFMA, prep fusion.
// Workspace (<=64 MiB), byte offsets:
//   [0..32M)  : qb@0, kb@8M, vb@16M, Wq|Wk|Wv@24M   (dead after proj)
//               -> reused as Opart fp32 [2][32][2048][64] (32 MiB) by flash
//   [32M..34M): Wo bf16 (live until gemm_out)
//   [34M..34.5M): mbits u64 [2048][32]
//   [34.5M..35M): lpart fp32 [2][32][2048]
//   [35M..43M): qhd  -> aliased by oc after flash (reduce writes oc here)
//   [43M..51M): khd   [51M..59M): vtd

using bf16x8 = __attribute__((ext_vector_type(8))) short;
using f32x4  = __attribute__((ext_vector_type(4))) float;

constexpr int Bc = 2, Sc = 2048, Dc = 1024, Hc = 16, DKc = 64;
constexpr int Mc = Bc * Sc;  // 4096
#define QSCALE 0.18033688011112042f  // log2(e)/sqrt(DK), folded into Q proj

__device__ __forceinline__ void lds_load16(const void* g, void* l) {
  __builtin_amdgcn_global_load_lds(
      (const __attribute__((address_space(1))) unsigned int*)g,
      (__attribute__((address_space(3))) unsigned int*)l, 16, 0, 0);
}

#if __has_builtin(__builtin_amdgcn_exp2f)
__device__ __forceinline__ float exp2_fast(float x) { return __builtin_amdgcn_exp2f(x); }
#else
__device__ __forceinline__ float exp2_fast(float x) {
  float r;
  asm("v_exp_f32 %0, %1\n\ts_nop 0" : "=v"(r) : "v"(x));
  return r;
}
#endif

// truncating bf16x2 pack: [hi16(b) : hi16(a)] — one v_perm_b32
__device__ __forceinline__ unsigned pack_trunc(float a, float b) {
  return __builtin_amdgcn_perm(__float_as_uint(b), __float_as_uint(a), 0x07060302u);
}

// RNE pack (epilogues)
__device__ __forceinline__ unsigned pack2bf(float a, float b) {
  union { __hip_bfloat16 h; unsigned short s; } ua, ub;
  ua.h = __float2bfloat16(a);
  ub.h = __float2bfloat16(b);
  return (unsigned)ua.s | ((unsigned)ub.s << 16);
}

// ---------------- prep: fused casts + mask pack ----------------
// blocks [0,12288): cast q/k/v (4096 each); [12288,16384): cast Wq/Wk/Wv/Wo
// (1024 each); [16384,32768): mask -> bit matrix.
__global__ void prep(const float* __restrict__ q, const float* __restrict__ k,
                     const float* __restrict__ v, const int* __restrict__ mask,
                     const float* __restrict__ Wq, const float* __restrict__ Wk,
                     const float* __restrict__ Wv, const float* __restrict__ Wo,
                     char* __restrict__ ws) {
  const size_t MB = 1024 * 1024;
  int blk = blockIdx.x;
  if (blk < 12288) {
    int which = blk >> 12;
    int i = (((blk & 4095) << 8) + threadIdx.x) * 4;
    const float* s = which == 0 ? q : (which == 1 ? k : v);
    __hip_bfloat16* d = (__hip_bfloat16*)(ws + (size_t)which * 8 * MB);
    float4 x = *(const float4*)&s[i];
    uint2 pk = {pack2bf(x.x, x.y), pack2bf(x.z, x.w)};
    *(uint2*)&d[i] = pk;
  } else if (blk < 16384) {
    int bb = blk - 12288;
    int which = bb >> 10;
    int i = (((bb & 1023) << 8) + threadIdx.x) * 4;
    const float* s = which == 0 ? Wq : (which == 1 ? Wk : (which == 2 ? Wv : Wo));
    __hip_bfloat16* d = which < 3 ? (__hip_bfloat16*)(ws + (24 + 2 * which) * MB)
                                  : (__hip_bfloat16*)(ws + 32 * MB);
    float4 x = *(const float4*)&s[i];
    uint2 pk = {pack2bf(x.x, x.y), pack2bf(x.z, x.w)};
    *(uint2*)&d[i] = pk;
  } else {
    int i = ((blk - 16384) << 8) + threadIdx.x;
    unsigned long long bal = __ballot(mask[i] != 0);
    if ((threadIdx.x & 63) == 0)
      ((unsigned long long*)(ws + 34 * MB))[i >> 6] = bal;
  }
}

// ---------------- fused QKV projection ----------------
// flat grid 768, XCD swizzle: all 24 n-blocks of one m-group on one XCD.
__global__ __launch_bounds__(256, 3) void proj_qkv(
    const __hip_bfloat16* __restrict__ qb, const __hip_bfloat16* __restrict__ kb,
    const __hip_bfloat16* __restrict__ vb, const __hip_bfloat16* __restrict__ Wcat,
    const float* __restrict__ bq, const float* __restrict__ bk,
    const float* __restrict__ bv, __hip_bfloat16* __restrict__ qhd,
    __hip_bfloat16* __restrict__ khd, __hip_bfloat16* __restrict__ vtd) {
  __shared__ __align__(16) __hip_bfloat16 As[128 * 64];
  __shared__ __align__(16) __hip_bfloat16 Bs[128 * 64];
  const int tid = threadIdx.x;
  const int f = blockIdx.x, g = f >> 3;
  const int m0 = ((f & 7) * 4 + g / 24) * 128;
  const int n0 = (g % 24) * 128;
  const int which = n0 >> 10, nl0 = n0 & 1023;
  const __hip_bfloat16* X = which == 0 ? qb : (which == 1 ? kb : vb);
  const float* bias = which == 0 ? bq : (which == 1 ? bk : bv);
  const int w = tid >> 6, lane = tid & 63, ln = lane & 15, quad = lane >> 4;
  const int swz = ((lane & 7) ^ (lane >> 3)) * 8;
  const int rk0 = ln * 128 + ((quad ^ (ln & 7)) * 16);
  const int rk1 = ln * 128 + (((quad + 4) ^ (ln & 7)) * 16);
  const int aoff = (m0 + w * 32 + (lane >> 3)) * 1024 + swz;
  const int boff = (n0 + w * 32 + (lane >> 3)) * 1024 + swz;
  char* aF = (char*)As + (w >> 1) * 8192;
  char* bF = (char*)Bs + (w & 1) * 8192;
  char* aDst = (char*)As + w * 4096 + lane * 16;
  char* bDst = (char*)Bs + w * 4096 + lane * 16;
  f32x4 acc[4][4] = {};
  int ko = 0;
  for (int kb64 = 0; kb64 < 16; ++kb64, ko += 64) {
#pragma unroll
    for (int i = 0; i < 4; ++i) {
      lds_load16(&X[aoff + i * 8192 + ko], aDst + i * 1024);
      lds_load16(&Wcat[boff + i * 8192 + ko], bDst + i * 1024);
    }
    __syncthreads();
    bf16x8 af[4][2], bf[4][2];
#pragma unroll
    for (int i = 0; i < 4; ++i) {
      af[i][0] = *(bf16x8*)(aF + i * 2048 + rk0);
      af[i][1] = *(bf16x8*)(aF + i * 2048 + rk1);
      bf[i][0] = *(bf16x8*)(bF + i * 2048 + rk0);
      bf[i][1] = *(bf16x8*)(bF + i * 2048 + rk1);
    }
#pragma unroll
    for (int i = 0; i < 4; ++i)
#pragma unroll
      for (int j = 0; j < 4; ++j) {
        acc[i][j] = __builtin_amdgcn_mfma_f32_16x16x32_bf16(af[i][0], bf[j][0],
                                                            acc[i][j], 0, 0, 0);
        acc[i][j] = __builtin_amdgcn_mfma_f32_16x16x32_bf16(af[i][1], bf[j][1],
                                                            acc[i][j], 0, 0, 0);
      }
    __syncthreads();
  }
  const int wm = (w >> 1) * 64, wn = (w & 1) * 64;
#pragma unroll
  for (int i = 0; i < 4; ++i)
#pragma unroll
    for (int j = 0; j < 4; ++j) {
      int ngl = nl0 + wn + j * 16 + ln;
      int mbase = m0 + wm + i * 16 + quad * 4;
      float bb = bias[ngl];
      float vv[4];
#pragma unroll
      for (int r = 0; r < 4; ++r) vv[r] = acc[i][j][r] + bb;
      int h = ngl >> 6, dk = ngl & 63;
      int b = mbase >> 11, s = mbase & 2047;
      if (which == 0) {
#pragma unroll
        for (int r = 0; r < 4; ++r)
          qhd[(((size_t)(b * Hc + h) * Sc + s + r) * DKc) + dk] =
              __float2bfloat16(vv[r] * QSCALE);
      } else if (which == 1) {
#pragma unroll
        for (int r = 0; r < 4; ++r)
          khd[(((size_t)(b * Hc + h) * Sc + s + r) * DKc) + dk] =
              __float2bfloat16(vv[r]);
      } else {
        uint2 pk = {pack2bf(vv[0], vv[1]), pack2bf(vv[2], vv[3])};
        *(uint2*)&vtd[(((size_t)(b * Hc + h) * DKc + dk) * Sc) + s] = pk;
      }
    }
}

// ---------------- out projection ----------------
// flat grid 512, XCD swizzle.
__global__ __launch_bounds__(256, 2) void gemm_out(
    const __hip_bfloat16* __restrict__ X, const __hip_bfloat16* __restrict__ W,
    const float* __restrict__ bias, float* __restrict__ Y) {
  __shared__ __align__(16) __hip_bfloat16 As[2][128 * 64];
  __shared__ __align__(16) __hip_bfloat16 Bs[2][64 * 64];
  const int tid = threadIdx.x;
  const int f = blockIdx.x, g = f >> 3;
  const int m0 = ((f & 7) * 4 + (g >> 4)) * 128;
  const int n0 = (g & 15) * 64;
  const int w = tid >> 6, lane = tid & 63, ln = lane & 15, quad = lane >> 4;
  const int wm = (w >> 1) * 64, wn = (w & 1) * 32;
  const int swz = ((lane & 7) ^ (lane >> 3)) * 8;
  const int rk0 = ln * 128 + ((quad ^ (ln & 7)) * 16);
  const int rk1 = ln * 128 + (((quad + 4) ^ (ln & 7)) * 16);
  const int aoff = (m0 + w * 32 + (lane >> 3)) * 1024 + swz;
  const int boff = (n0 + w * 16 + (lane >> 3)) * 1024 + swz;
  f32x4 acc[4][2] = {};

#define OSTAGE(KO, BI)                                                        \
  {                                                                           \
    _Pragma("unroll") for (int i = 0; i < 4; ++i)                             \
        lds_load16(&X[aoff + i * 8192 + (KO)],                                \
                   (char*)As[BI] + w * 4096 + lane * 16 + i * 1024);          \
    _Pragma("unroll") for (int i = 0; i < 2; ++i)                             \
        lds_load16(&W[boff + i * 8192 + (KO)],                                \
                   (char*)Bs[BI] + w * 2048 + lane * 16 + i * 1024);          \
  }

  OSTAGE(0, 0);
  for (int kb64 = 0; kb64 < 16; ++kb64) {
    const int bi = kb64 & 1;
    __syncthreads();
    if (kb64 + 1 < 16) OSTAGE((kb64 + 1) * 64, bi ^ 1);
    bf16x8 af[4][2], bf[2][2];
#pragma unroll
    for (int i = 0; i < 4; ++i) {
      af[i][0] = *(bf16x8*)((char*)As[bi] + wm * 128 + i * 2048 + rk0);
      af[i][1] = *(bf16x8*)((char*)As[bi] + wm * 128 + i * 2048 + rk1);
    }
#pragma unroll
    for (int j = 0; j < 2; ++j) {
      bf[j][0] = *(bf16x8*)((char*)Bs[bi] + wn * 128 + j * 2048 + rk0);
      bf[j][1] = *(bf16x8*)((char*)Bs[bi] + wn * 128 + j * 2048 + rk1);
    }
#pragma unroll
    for (int i = 0; i < 4; ++i)
#pragma unroll
      for (int j = 0; j < 2; ++j) {
        acc[i][j] = __builtin_amdgcn_mfma_f32_16x16x32_bf16(af[i][0], bf[j][0],
                                                            acc[i][j], 0, 0, 0);
        acc[i][j] = __builtin_amdgcn_mfma_f32_16x16x32_bf16(af[i][1], bf[j][1],
                                                            acc[i][j], 0, 0, 0);
      }
  }
#pragma unroll
  for (int i = 0; i < 4; ++i)
#pragma unroll
    for (int j = 0; j < 2; ++j) {
      int ng = n0 + wn + j * 16 + ln;
      int mbase = m0 + wm + i * 16 + quad * 4;
      float bb = bias[ng];
#pragma unroll
      for (int r = 0; r < 4; ++r)
        Y[(size_t)(mbase + r) * Dc + ng] = acc[i][j][r] + bb;
    }
}

// ---------------- flash attention (t-split, partial output) ----------------
// flat grid 1024: (half,bh,q0) XCD-swizzled. Partials are exactly additive
// (no-max softmax). l computed via ones-MFMA. Epilogue: plain float4 stores.
__global__ __launch_bounds__(256, 3) void flash_attn(
    const __hip_bfloat16* __restrict__ qh, const __hip_bfloat16* __restrict__ kh,
    const __hip_bfloat16* __restrict__ vt, const uint4* __restrict__ mb4,
    float* __restrict__ opart, float* __restrict__ lpart) {
  __shared__ __align__(16) char L[51200];
  const int tid = threadIdx.x;
  const int f = blockIdx.x, g = f >> 3;
  const int bhh = (f & 7) * 8 + (g >> 4);  // 0..63
  const int q0 = (g & 15) * 128;
  const int half = bhh >> 5, bh = bhh & 31;
  const int w = tid >> 6, lane = tid & 63, ln = lane & 15, quad = lane >> 4;
  const size_t base = (size_t)bh * Sc * DKc;
  const __hip_bfloat16* khb = kh + base + half * 65536;  // 1024 K-rows per half
  const __hip_bfloat16* vtb = vt + base;

  bf16x8 qf[2][2];
#pragma unroll
  for (int qt = 0; qt < 2; ++qt)
#pragma unroll
    for (int kc = 0; kc < 2; ++kc)
      qf[qt][kc] = *(const bf16x8*)&qh[base +
          (size_t)(q0 + w * 32 + qt * 16 + ln) * 64 + kc * 32 + quad * 8];

  bf16x8 onesA;
#pragma unroll
  for (int i = 0; i < 8; ++i) onesA[i] = (short)0x3F80;  // bf16 1.0

  const int swz = ((lane & 7) ^ (lane >> 3)) * 8;
  const int rk0 = ln * 128 + ((quad ^ (ln & 7)) * 16);
  const int rk1 = ln * 128 + (((quad + 4) ^ (ln & 7)) * 16);
  const int rPw = 32768 + w * 4608 + ln * 144 + quad * 8;
  const int rPb = 32768 + w * 4608 + ln * 144 + quad * 16;
  char* dmaL = L + w * 2048 + lane * 16;
  int koff = (w * 16 + (lane >> 3)) * 64 + swz;
  int voff0 = (w * 16 + (lane >> 3)) * Sc + swz + half * 1024;
  int voff1 = voff0 + 8 * Sc;
  int midx0 = (q0 + w * 32 + ln) * 16 + half * 8;
  int midx1 = midx0 + 256;
  const int sh0 = quad * 4, sh1 = quad * 4 + 16;

#define KV_DMA(BI)                                                            \
  {                                                                           \
    lds_load16(khb + koff, dmaL + (BI)*8192);                                 \
    lds_load16(khb + koff + 512, dmaL + (BI)*8192 + 1024);                    \
    lds_load16(vtb + voff0, dmaL + 16384 + (BI)*8192);                        \
    lds_load16(vtb + voff1, dmaL + 16384 + (BI)*8192 + 1024);                 \
  }

  f32x4 Oacc[4][2] = {};
  f32x4 lacc[2] = {};
  KV_DMA(0);

#define FTILE(BUF, LO0, HI0, LO1, HI1)                                        \
  {                                                                           \
    bf16x8 kf[4][2];                                                          \
    _Pragma("unroll") for (int tt = 0; tt < 4; ++tt) {                        \
      kf[tt][0] = *(bf16x8*)(L + (BUF)*8192 + tt * 2048 + rk0);               \
      kf[tt][1] = *(bf16x8*)(L + (BUF)*8192 + tt * 2048 + rk1);               \
    }                                                                         \
    _Pragma("unroll") for (int qt = 0; qt < 2; ++qt) {                        \
      f32x4 s[4];                                                             \
      _Pragma("unroll") for (int tt = 0; tt < 4; ++tt) {                      \
        f32x4 z = {0.f, 0.f, 0.f, 0.f};                                       \
        z = __builtin_amdgcn_mfma_f32_16x16x32_bf16(kf[tt][0], qf[qt][0], z,  \
                                                    0, 0, 0);                 \
        s[tt] = __builtin_amdgcn_mfma_f32_16x16x32_bf16(kf[tt][1], qf[qt][1], \
                                                        z, 0, 0, 0);          \
      }                                                                       \
      unsigned lo = qt ? (LO1) : (LO0), hi = qt ? (HI1) : (HI0);              \
      _Pragma("unroll") for (int tt = 0; tt < 4; ++tt) {                      \
        unsigned word = (tt & 2) ? hi : lo;                                   \
        unsigned pre = word >> ((tt & 1) ? sh1 : sh0);                        \
        float p[4];                                                           \
        _Pragma("unroll") for (int r = 0; r < 4; ++r) {                       \
          float e = exp2_fast(s[tt][r]);                                      \
          p[r] = (pre & (1u << r)) ? e : 0.f;                                 \
        }                                                                     \
        uint2 pk = {pack_trunc(p[0], p[1]), pack_trunc(p[2], p[3])};          \
        *(uint2*)(L + rPw + qt * 2304 + tt * 32) = pk;                        \
      }                                                                       \
    }                                                                         \
    bf16x8 vf[4][2], pb[2][2];                                                \
    _Pragma("unroll") for (int dt = 0; dt < 4; ++dt) {                        \
      vf[dt][0] = *(bf16x8*)(L + 16384 + (BUF)*8192 + dt * 2048 + rk0);       \
      vf[dt][1] = *(bf16x8*)(L + 16384 + (BUF)*8192 + dt * 2048 + rk1);       \
    }                                                                         \
    _Pragma("unroll") for (int qt = 0; qt < 2; ++qt) {                        \
      pb[qt][0] = *(bf16x8*)(L + rPb + qt * 2304);                            \
      pb[qt][1] = *(bf16x8*)(L + rPb + qt * 2304 + 64);                       \
    }                                                                         \
    _Pragma("unroll") for (int qt = 0; qt < 2; ++qt) {                        \
      lacc[qt] = __builtin_amdgcn_mfma_f32_16x16x32_bf16(onesA, pb[qt][0],    \
                                                         lacc[qt], 0, 0, 0);  \
      lacc[qt] = __builtin_amdgcn_mfma_f32_16x16x32_bf16(onesA, pb[qt][1],    \
                                                         lacc[qt], 0, 0, 0);  \
    }                                                                         \
    _Pragma("unroll") for (int dt = 0; dt < 4; ++dt)                          \
        _Pragma("unroll") for (int qt = 0; qt < 2; ++qt) {                    \
      Oacc[dt][qt] = __builtin_amdgcn_mfma_f32_16x16x32_bf16(                 \
          vf[dt][0], pb[qt][0], Oacc[dt][qt], 0, 0, 0);                       \
      Oacc[dt][qt] = __builtin_amdgcn_mfma_f32_16x16x32_bf16(                 \
          vf[dt][1], pb[qt][1], Oacc[dt][qt], 0, 0, 0);                       \
    }                                                                         \
  }

  for (int it2 = 0; it2 < 8; ++it2) {
    __syncthreads();
    uint4 mq0 = mb4[midx0], mq1 = mb4[midx1];
    ++midx0; ++midx1;
    koff += 4096; voff0 += 64; voff1 += 64;
    KV_DMA(1);
    FTILE(0, mq0.x, mq0.y, mq1.x, mq1.y);
    __syncthreads();
    if (it2 < 7) {
      koff += 4096; voff0 += 64; voff1 += 64;
      KV_DMA(0);
    }
    FTILE(1, mq0.z, mq0.w, mq1.z, mq1.w);
  }

  // epilogue: store fp32 partial O^T (C-layout: col=q, row=dk) + partial l
  const size_t obase = (size_t)(half * 32 + bh) * 2048;
#pragma unroll
  for (int qt = 0; qt < 2; ++qt) {
    int qrow = q0 + w * 32 + qt * 16 + ln;
#pragma unroll
    for (int dt = 0; dt < 4; ++dt) {
      f32x4 o = Oacc[dt][qt];
      float4 st = {o[0], o[1], o[2], o[3]};
      *(float4*)&opart[(obase + qrow) * 64 + dt * 16 + quad * 4] = st;
    }
    if (quad == 0) lpart[obase + qrow] = lacc[qt][0];
  }
}

// ---------------- reduce: combine halves, normalize, write oc bf16 ----------
__global__ void reduce_o(const float* __restrict__ opart,
                         const float* __restrict__ lpart,
                         __hip_bfloat16* __restrict__ oc) {
  int t = blockIdx.x * 256 + threadIdx.x;  // 0..524287
  int r = t >> 3, dk8 = (t & 7) * 8;
  const size_t HS = (size_t)32 * 2048 * 64;  // half stride in floats
  float4 a0 = *(const float4*)&opart[(size_t)r * 64 + dk8];
  float4 a1 = *(const float4*)&opart[(size_t)r * 64 + dk8 + 4];
  float4 b0 = *(const float4*)&opart[HS + (size_t)r * 64 + dk8];
  float4 b1 = *(const float4*)&opart[HS + (size_t)r * 64 + dk8 + 4];
  float li = 1.f / fmaxf(lpart[r] + lpart[65536 + r], 1e-30f);
  int bh = r >> 11, qq = r & 2047, b = bh >> 4, h = bh & 15;
  uint4 o;
  o.x = pack2bf((a0.x + b0.x) * li, (a0.y + b0.y) * li);
  o.y = pack2bf((a0.z + b0.z) * li, (a0.w + b0.w) * li);
  o.z = pack2bf((a1.x + b1.x) * li, (a1.y + b1.y) * li);
  o.w = pack2bf((a1.z + b1.z) * li, (a1.w + b1.w) * li);
  *(uint4*)&oc[((size_t)(b * Sc + qq) * Dc) + h * 64 + dk8] = o;
}

extern "C" void kernel_launch(void* const* d_in, const int* in_sizes, int n_in,
                              void* d_out, int out_size, void* d_ws, size_t ws_size,
                              hipStream_t stream) {
  const float* q  = (const float*)d_in[0];
  const float* k  = (const float*)d_in[1];
  const float* v  = (const float*)d_in[2];
  const int* mask = (const int*)d_in[3];
  const float* Wq = (const float*)d_in[4];
  const float* bq = (const float*)d_in[5];
  const float* Wk = (const float*)d_in[6];
  const float* bk = (const float*)d_in[7];
  const float* Wv = (const float*)d_in[8];
  const float* bv = (const float*)d_in[9];
  const float* Wo = (const float*)d_in[10];
  const float* bo = (const float*)d_in[11];

  char* ws = (char*)d_ws;
  const size_t MB = 1024 * 1024;
  __hip_bfloat16* qb   = (__hip_bfloat16*)(ws + 0 * MB);
  __hip_bfloat16* kb   = (__hip_bfloat16*)(ws + 8 * MB);
  __hip_bfloat16* vb   = (__hip_bfloat16*)(ws + 16 * MB);
  __hip_bfloat16* Wcat = (__hip_bfloat16*)(ws + 24 * MB);  // Wq|Wk|Wv
  float*          opart = (float*)(ws + 0 * MB);           // aliases qb..Wcat
  __hip_bfloat16* Wob  = (__hip_bfloat16*)(ws + 32 * MB);
  uint4*          mb4  = (uint4*)(ws + 34 * MB);
  float*          lpart = (float*)(ws + 34 * MB + 512 * 1024);
  __hip_bfloat16* qhd  = (__hip_bfloat16*)(ws + 35 * MB);
  __hip_bfloat16* oc   = (__hip_bfloat16*)(ws + 35 * MB);  // aliases qhd
  __hip_bfloat16* khd  = (__hip_bfloat16*)(ws + 43 * MB);
  __hip_bfloat16* vtd  = (__hip_bfloat16*)(ws + 51 * MB);

  prep<<<32768, 256, 0, stream>>>(q, k, v, mask, Wq, Wk, Wv, Wo, ws);
  proj_qkv<<<768, 256, 0, stream>>>(qb, kb, vb, Wcat, bq, bk, bv, qhd, khd, vtd);
  flash_attn<<<1024, 256, 0, stream>>>(qhd, khd, vtd, mb4, opart, lpart);
  reduce_o<<<2048, 256, 0, stream>>>(opart, lpart, oc);
  gemm_out<<<512, 256, 0, stream>>>(oc, Wob, bo, (float*)d_out);
}